// Round 5
// baseline (69.692 us; speedup 1.0000x reference)
//
#include <hip/hip_runtime.h>
#include <math.h>

#pragma clang fp contract(off)

#define NA      896
#define MAXDET  256
#define NBATCH  512
#define CAP     192
#define NCHUNK  14

typedef unsigned long long u64;
typedef unsigned int u32;

// ---------------- fast path: C <= 192, one batch per 4-wave block ----------
// No global serial scan: overlap-graph connected components are peeled
// independently (picks are strictly increasing in sorted index, clusters
// stay within components), then emitted by pick-rank.
__global__ __launch_bounds__(256, 1) void nms_fast(
    const float* __restrict__ raw_box,
    const float* __restrict__ raw_score,
    const float* __restrict__ anchors,
    float* __restrict__ out,
    float* __restrict__ flags,
    int* __restrict__ ws, int use_ws)
{
    __shared__ float  det[CAP][17];
    __shared__ float4 sbox[CAP];
    __shared__ u64    keys[CAP];
    __shared__ int    slot_a[CAP];
    __shared__ float  slot_s[CAP];
    __shared__ int    srt_a[CAP];
    __shared__ u64    mat0[CAP], mat1[CAP], mat2[CAP];
    __shared__ u64    pcl0[CAP], pcl1[CAP], pcl2[CAP];
    __shared__ u32    memw[CAP][6];
    __shared__ int    label[CAP];
    __shared__ int    pickn[CAP];
    __shared__ u64    pmsh[3];
    __shared__ int    cnt[NCHUNK];
    __shared__ int    chg;
    __shared__ int    stuck;

    const int b    = blockIdx.x;
    const int tid  = threadIdx.x;
    const int lane = tid & 63;
    const int wv   = tid >> 6;

    const float* sc_base = raw_score + (size_t)b * NA;
    float* out_b = out   + (size_t)b * MAXDET * 17;
    float* flg_b = flags + (size_t)b * MAXDET;

    // ---- Phase 1a: scores + per-chunk ballots ----
    float s_r[4]; u64 bal_r[4]; bool v_r[4];
    #pragma unroll
    for (int it = 0; it < 4; ++it) {
        int c = wv + it * 4;
        s_r[it] = 0.0f; bal_r[it] = 0ull; v_r[it] = false;
        if (c < NCHUNK) {
            float x = sc_base[c * 64 + lane];
            x = fminf(fmaxf(x, -100.0f), 100.0f);
            float s = 1.0f / (1.0f + expf(-x));
            bool v = (s >= 0.75f);
            u64 bal = __ballot(v);
            s_r[it] = s; bal_r[it] = bal; v_r[it] = v;
            if (lane == 0) cnt[c] = (int)__popcll(bal);
        }
    }
    // early zero-fill of the whole output tile (emission overwrites later;
    // barriers between guarantee ordering). Fallback blocks get rewritten.
    for (int t = tid; t < MAXDET * 17; t += 256) out_b[t] = 0.0f;
    for (int t = tid; t < MAXDET;      t += 256) flg_b[t] = 0.0f;
    // misc init
    if (tid == 0) stuck = CAP;
    if (tid < CAP) {
        pickn[tid] = 0;
        #pragma unroll
        for (int w_ = 0; w_ < 6; ++w_) memw[tid][w_] = 0u;
    }
    __syncthreads();

    // ---- Phase 1b: prefix + scatter ----
    int cn[NCHUNK];
    #pragma unroll
    for (int j = 0; j < NCHUNK; ++j) cn[j] = cnt[j];
    int C = 0;
    #pragma unroll
    for (int j = 0; j < NCHUNK; ++j) C += cn[j];
    if (use_ws && tid == 0) ws[b] = C;
    if (C > CAP) return;   // uniform; fallback kernel owns this block
    #pragma unroll
    for (int it = 0; it < 4; ++it) {
        int c = wv + it * 4;
        if (c < NCHUNK && v_r[it]) {
            int base = 0;
            #pragma unroll
            for (int j = 0; j < NCHUNK; ++j) base += (j < c) ? cn[j] : 0;
            int slot = base + (int)__popcll(bal_r[it] & ((1ull << lane) - 1ull));
            keys[slot]   = ((u64)__float_as_uint(s_r[it]) << 8) | (u64)(255 - slot);
            slot_a[slot] = c * 64 + lane;
            slot_s[slot] = s_r[it];
        }
    }
    __syncthreads();

    // ---- Phase 2: rank-by-count sort (keys unique) ----
    {
        u64 myk = (tid < C) ? keys[tid] : 0ull;
        int q = 0;
        #pragma unroll 4
        for (int i = 0; i < C; ++i) q += (keys[i] > myk) ? 1 : 0;
        if (tid < C) { srt_a[q] = slot_a[tid]; det[q][16] = slot_s[tid]; }
    }
    __syncthreads();

    // ---- Phase 3: decode (one sorted row per thread) ----
    if (tid < C) {
        int a = srt_a[tid];
        const float4 an = ((const float4*)anchors)[a];
        const float4* rb = (const float4*)(raw_box + ((size_t)b * NA + a) * 16);
        float4 r0 = rb[0], r1 = rb[1], r2 = rb[2], r3 = rb[3];
        float ax = an.x, ay = an.y, aw = an.z, ah = an.w;
        float xc = r0.x / 128.0f * aw + ax;
        float yc = r0.y / 128.0f * ah + ay;
        float w  = r0.z / 128.0f * aw;
        float h  = r0.w / 128.0f * ah;
        float d0 = yc - h * 0.5f, d1 = xc - w * 0.5f;
        float d2 = yc + h * 0.5f, d3 = xc + w * 0.5f;
        det[tid][0] = d0; det[tid][1] = d1; det[tid][2] = d2; det[tid][3] = d3;
        sbox[tid] = make_float4(d0, d1, d2, d3);
        float kp[12] = {r1.x, r1.y, r1.z, r1.w,
                        r2.x, r2.y, r2.z, r2.w,
                        r3.x, r3.y, r3.z, r3.w};
        #pragma unroll
        for (int t = 0; t < 6; ++t) {
            det[tid][4 + 2 * t] = kp[2 * t]     / 128.0f * aw + ax;
            det[tid][5 + 2 * t] = kp[2 * t + 1] / 128.0f * ah + ay;
        }
    }
    __syncthreads();

    // ---- Phase 4: overlap bitmatrix, one row per thread (symmetric) ----
    if (tid < C) {
        float4 sb = sbox[tid];
        float bx = sb.x, by = sb.y, bz = sb.z, bw = sb.w;
        float ar = (bz - bx) * (bw - by);
        u64 mw0 = 0, mw1 = 0, mw2 = 0;
        #pragma unroll
        for (int w_ = 0; w_ < 3; ++w_) {
            int base = w_ * 64;
            int ke = C - base; if (ke > 64) ke = 64;
            u64 mm = 0, bit = 1ull;
            #pragma unroll 4
            for (int k = 0; k < ke; ++k, bit <<= 1) {
                float4 bk = sbox[base + k];
                float ak = (bk.z - bk.x) * (bk.w - bk.y);
                float i0 = fmaxf(bx, bk.x), i1 = fmaxf(by, bk.y);
                float i2 = fminf(bz, bk.z), i3 = fminf(bw, bk.w);
                float inter = (i2 - i0) * (i3 - i1);
                float qq = inter / (ar + ak - inter);  // NaN -> no bit
                if (qq > 0.3f) mm |= bit;
            }
            if (w_ == 0) mw0 = mm; else if (w_ == 1) mw1 = mm; else mw2 = mm;
        }
        mat0[tid] = mw0; mat1[tid] = mw1; mat2[tid] = mw2;
    }
    if (tid < CAP) label[tid] = tid;
    __syncthreads();

    // ---- Phase 5a: connected components (min-label prop + pointer jumps) ----
    for (int round = 0; round < 64; ++round) {
        if (tid == 0) chg = 0;
        __syncthreads();
        bool my = false;
        if (tid < C) {
            int l = label[tid];
            int nl = l;
            u64 m = mat0[tid];
            while (m) { int k = __builtin_ctzll(m); m &= m - 1;
                        int lk = label[k]; nl = nl < lk ? nl : lk; }
            m = mat1[tid];
            while (m) { int k = 64 + __builtin_ctzll(m); m &= m - 1;
                        int lk = label[k]; nl = nl < lk ? nl : lk; }
            m = mat2[tid];
            while (m) { int k = 128 + __builtin_ctzll(m); m &= m - 1;
                        int lk = label[k]; nl = nl < lk ? nl : lk; }
            int j1 = label[nl]; nl = nl < j1 ? nl : j1;
            j1 = label[nl];     nl = nl < j1 ? nl : j1;
            j1 = label[nl];     nl = nl < j1 ? nl : j1;
            if (nl < l) { label[tid] = nl; my = true; }
        }
        if (my) chg = 1;
        __syncthreads();
        int c_ = chg;
        __syncthreads();
        if (!c_) break;
    }

    // ---- Phase 5b: member masks per root ----
    if (tid < C) {
        int root = label[tid];
        atomicOr(&memw[root][tid >> 5], 1u << (tid & 31));
    }
    __syncthreads();

    // ---- Phase 5c: per-component peel (roots walk concurrently) ----
    if (tid < C && label[tid] == tid) {
        u64 r0 = (u64)memw[tid][0] | ((u64)memw[tid][1] << 32);
        u64 r1 = (u64)memw[tid][2] | ((u64)memw[tid][3] << 32);
        u64 r2 = (u64)memw[tid][4] | ((u64)memw[tid][5] << 32);
        int guard = 0;
        while ((r0 | r1 | r2) && guard < CAP) {
            ++guard;
            int i;
            if      (r0) i = __builtin_ctzll(r0);
            else if (r1) i = 64 + __builtin_ctzll(r1);
            else         i = 128 + __builtin_ctzll(r2);
            u64 w0 = mat0[i], w1 = mat1[i], w2 = mat2[i];
            u64 c0 = r0 & w0, c1 = r1 & w1, c2 = r2 & w2;
            // self-bit must be in the cluster (self-IoU == 1 normally);
            // otherwise reference semantics freeze the scan -> stuck path.
            bool selfin = (i < 64)  ? ((c0 >> i) & 1ull)
                        : (i < 128) ? ((c1 >> (i - 64)) & 1ull)
                                    : ((c2 >> (i - 128)) & 1ull);
            if (!selfin) { atomicMin(&stuck, i); break; }
            int n = (int)__popcll(c0) + (int)__popcll(c1) + (int)__popcll(c2);
            pcl0[i] = c0; pcl1[i] = c1; pcl2[i] = c2; pickn[i] = n;
            r0 &= ~c0; r1 &= ~c1; r2 &= ~c2;
        }
    }
    __syncthreads();

    // ---- Phase 5d: picks -> step ranks ----
    const int stuck_v = stuck;
    const bool is_pick = (tid < C) && (pickn[tid] > 0) && (tid < stuck_v);
    {
        u64 bal = __ballot(is_pick);
        if (lane == 0 && wv < 3) pmsh[wv] = bal;
        if (tid == 255) { /* keep wave3 converged */ }
    }
    __syncthreads();
    const u64 pm0 = pmsh[0], pm1 = pmsh[1], pm2 = pmsh[2];
    const int P = (int)__popcll(pm0) + (int)__popcll(pm1) + (int)__popcll(pm2);

    // ---- Phase 6: parallel emission by rank ----
    if (is_pick) {
        u64 lanemask = (1ull << lane) - 1ull;
        int s;
        if (wv == 0)      s = (int)__popcll(pm0 & lanemask);
        else if (wv == 1) s = (int)__popcll(pm0) + (int)__popcll(pm1 & lanemask);
        else              s = (int)__popcll(pm0) + (int)__popcll(pm1)
                            + (int)__popcll(pm2 & lanemask);
        float* orow = out_b + s * 17;
        int n = pickn[tid];
        if (n <= 1) {
            #pragma unroll
            for (int c = 0; c < 17; ++c) orow[c] = det[tid][c];
        } else {
            float tot = 0.0f, wc[16];
            #pragma unroll
            for (int c = 0; c < 16; ++c) wc[c] = 0.0f;
            u64 m = pcl0[tid];
            while (m) { int k = __builtin_ctzll(m); m &= m - 1;
                float sc = det[k][16]; tot += sc;
                #pragma unroll
                for (int c = 0; c < 16; ++c) wc[c] += det[k][c] * sc; }
            m = pcl1[tid];
            while (m) { int k = 64 + __builtin_ctzll(m); m &= m - 1;
                float sc = det[k][16]; tot += sc;
                #pragma unroll
                for (int c = 0; c < 16; ++c) wc[c] += det[k][c] * sc; }
            m = pcl2[tid];
            while (m) { int k = 128 + __builtin_ctzll(m); m &= m - 1;
                float sc = det[k][16]; tot += sc;
                #pragma unroll
                for (int c = 0; c < 16; ++c) wc[c] += det[k][c] * sc; }
            float safe = (tot > 0.0f) ? tot : 1.0f;
            #pragma unroll
            for (int c = 0; c < 16; ++c) orow[c] = wc[c] / safe;
            orow[16] = tot / (float)n;
        }
        flg_b[s] = 1.0f;
    }
    // frozen-tail replication for the (unreachable) stuck case
    if (stuck_v < CAP) {
        for (int s2 = P + tid; s2 < MAXDET; s2 += 256) {
            float* orow = out_b + s2 * 17;
            #pragma unroll
            for (int c = 0; c < 17; ++c) orow[c] = det[stuck_v][c];
            flg_b[s2] = 1.0f;
        }
    }
}

// ---------------- fallback: C > 192 (statistically unreachable) ------------
__global__ __launch_bounds__(64, 1) void nms_fallback(
    const float* __restrict__ raw_box,
    const float* __restrict__ raw_score,
    const float* __restrict__ anchors,
    float* __restrict__ out,
    float* __restrict__ flags,
    const int* __restrict__ ws, int use_ws)
{
    const int b    = blockIdx.x;
    const int lane = threadIdx.x;
    if (use_ws && ws[b] <= CAP) return;   // cheap early-out

    __shared__ float det[NA][17];
    __shared__ int   cand_a[NA];

    int C = 0;
    const float* sc_base = raw_score + (size_t)b * NA;
    #pragma unroll
    for (int c = 0; c < NA / 64; ++c) {
        int a = c * 64 + lane;
        float x = sc_base[a];
        x = fminf(fmaxf(x, -100.0f), 100.0f);
        float s = 1.0f / (1.0f + expf(-x));
        bool v = (s >= 0.75f);
        u64 bal = __ballot(v);
        if (v) {
            int slot = C + (int)__popcll(bal & ((1ull << lane) - 1ull));
            cand_a[slot]  = a;
            det[slot][16] = s;
        }
        C += (int)__popcll(bal);
    }
    if (C <= CAP) return;   // fast kernel owns this block
    __syncthreads();

    for (int k = lane; k < C; k += 64) {
        int a = cand_a[k];
        const float4 an = ((const float4*)anchors)[a];
        const float4* rb = (const float4*)(raw_box + ((size_t)b * NA + a) * 16);
        float4 r0 = rb[0], r1 = rb[1], r2 = rb[2], r3 = rb[3];
        float ax = an.x, ay = an.y, aw = an.z, ah = an.w;
        float xc = r0.x / 128.0f * aw + ax;
        float yc = r0.y / 128.0f * ah + ay;
        float w  = r0.z / 128.0f * aw;
        float h  = r0.w / 128.0f * ah;
        det[k][0] = yc - h * 0.5f;
        det[k][1] = xc - w * 0.5f;
        det[k][2] = yc + h * 0.5f;
        det[k][3] = xc + w * 0.5f;
        float kp[12] = {r1.x, r1.y, r1.z, r1.w,
                        r2.x, r2.y, r2.z, r2.w,
                        r3.x, r3.y, r3.z, r3.w};
        #pragma unroll
        for (int t = 0; t < 6; ++t) {
            det[k][4 + 2 * t] = kp[2 * t]     / 128.0f * aw + ax;
            det[k][5 + 2 * t] = kp[2 * t + 1] / 128.0f * ah + ay;
        }
    }
    __syncthreads();

    const int nj = (C + 63) >> 6;
    unsigned int rem = 0;
    for (int j = 0; j < nj; ++j)
        if (lane + (j << 6) < C) rem |= (1u << j);

    float* out_b = out   + (size_t)b * MAXDET * 17;
    float* flg_b = flags + (size_t)b * MAXDET;

    int step = 0;
    for (; step < MAXDET; ++step) {
        u64 best = 0;
        for (int j = 0; j < nj; ++j) {
            if (rem & (1u << j)) {
                int k = lane + (j << 6);
                u64 key = ((u64)__float_as_uint(det[k][16]) << 10) |
                          (u64)(1023 - k);
                if (key > best) best = key;
            }
        }
        #pragma unroll
        for (int off = 32; off; off >>= 1) {
            u64 o = __shfl_xor(best, off);
            if (o > best) best = o;
        }
        if (best == 0) break;
        int idx = 1023 - (int)(best & 1023ull);

        float bx0 = det[idx][0], bx1 = det[idx][1];
        float bx2 = det[idx][2], bx3 = det[idx][3];
        float areaA = (bx2 - bx0) * (bx3 - bx1);

        unsigned int ov = 0;
        for (int j = 0; j < nj; ++j) {
            if (rem & (1u << j)) {
                int k = lane + (j << 6);
                float c0 = det[k][0], c1 = det[k][1];
                float c2 = det[k][2], c3 = det[k][3];
                float i0 = fmaxf(bx0, c0);
                float i1 = fmaxf(bx1, c1);
                float i2 = fminf(bx2, c2);
                float i3 = fminf(bx3, c3);
                float inter = (i2 - i0) * (i3 - i1);
                float areaB = (c2 - c0) * (c3 - c1);
                float q = inter / (areaA + areaB - inter);
                if (q > 0.3f) ov |= (1u << j);
            }
        }
        rem &= ~ov;

        int n = 0;
        for (int j = 0; j < nj; ++j)
            n += (int)__popcll(__ballot((ov >> j) & 1u));

        if (n <= 1) {
            if (lane < 17) out_b[step * 17 + lane] = det[idx][lane];
            if (lane == 17) flg_b[step] = 1.0f;
        } else {
            float tot = 0.0f, wc[16];
            #pragma unroll
            for (int c = 0; c < 16; ++c) wc[c] = 0.0f;
            for (int j = 0; j < nj; ++j) {
                if (ov & (1u << j)) {
                    int k = lane + (j << 6);
                    float s = det[k][16];
                    tot += s;
                    #pragma unroll
                    for (int c = 0; c < 16; ++c) wc[c] += det[k][c] * s;
                }
            }
            #pragma unroll
            for (int off = 32; off; off >>= 1) {
                tot += __shfl_xor(tot, off);
                #pragma unroll
                for (int c = 0; c < 16; ++c) wc[c] += __shfl_xor(wc[c], off);
            }
            if (lane == 0) {
                float safe = (tot > 0.0f) ? tot : 1.0f;
                #pragma unroll
                for (int c = 0; c < 16; ++c) out_b[step * 17 + c] = wc[c] / safe;
                out_b[step * 17 + 16] = tot / (float)n;
                flg_b[step] = 1.0f;
            }
        }
    }

    for (int t = step * 17 + lane; t < MAXDET * 17; t += 64) out_b[t] = 0.0f;
    for (int t = step + lane;      t < MAXDET;      t += 64) flg_b[t] = 0.0f;
}

extern "C" void kernel_launch(void* const* d_in, const int* in_sizes, int n_in,
                              void* d_out, int out_size, void* d_ws, size_t ws_size,
                              hipStream_t stream) {
    const float* raw_box   = (const float*)d_in[0];
    const float* raw_score = (const float*)d_in[1];
    const float* anchors   = (const float*)d_in[2];
    float* out   = (float*)d_out;
    float* flags = out + (size_t)NBATCH * MAXDET * 17;
    int use_ws = (ws_size >= NBATCH * sizeof(int)) ? 1 : 0;
    nms_fast    <<<NBATCH, 256, 0, stream>>>(raw_box, raw_score, anchors, out, flags,
                                             (int*)d_ws, use_ws);
    nms_fallback<<<NBATCH, 64, 0, stream>>>(raw_box, raw_score, anchors, out, flags,
                                            (const int*)d_ws, use_ws);
}

// Round 6
// 41.959 us; speedup vs baseline: 1.6609x; 1.6609x over previous
//
#include <hip/hip_runtime.h>
#include <math.h>

#pragma clang fp contract(off)

#define NA      896
#define MAXDET  256
#define NBATCH  512
#define CAP     192
#define NCHUNK  14

typedef unsigned long long u64;
typedef unsigned int u32;

__device__ __forceinline__ u64 rl64(u64 v, int l) {
    u32 lo = __builtin_amdgcn_readlane((u32)v, l);
    u32 hi = __builtin_amdgcn_readlane((u32)(v >> 32), l);
    return ((u64)hi << 32) | (u64)lo;
}

// ---------------- fast path: C <= 192, one batch per 4-wave block ----------
// Serial scan reduced to pick-set computation only (rem &= ~row(pick));
// clusters recovered in parallel via fc(k) = first pick covering k, using
// bit-exact symmetry of the IoU test. Emission by pick-rank.
__global__ __launch_bounds__(256, 1) void nms_fast(
    const float* __restrict__ raw_box,
    const float* __restrict__ raw_score,
    const float* __restrict__ anchors,
    float* __restrict__ out,
    float* __restrict__ flags,
    int* __restrict__ ws, int use_ws)
{
    __shared__ float  det[CAP][17];
    __shared__ float4 sbox[CAP];
    __shared__ u64    keys[CAP];
    __shared__ int    slot_a[CAP];
    __shared__ float  slot_s[CAP];
    __shared__ int    srt_a[CAP];
    __shared__ u64    mat0[CAP], mat1[CAP], mat2[CAP];
    __shared__ u32    cl[CAP][6];
    __shared__ u64    Psh[3];
    __shared__ int    stuck_sh;
    __shared__ int    cnt[NCHUNK];

    const int b    = blockIdx.x;
    const int tid  = threadIdx.x;
    const int lane = tid & 63;
    const int wv   = tid >> 6;

    const float* sc_base = raw_score + (size_t)b * NA;
    float* out_b = out   + (size_t)b * MAXDET * 17;
    float* flg_b = flags + (size_t)b * MAXDET;

    // ---- Phase 1a: scores + per-chunk ballots; init cl[] ----
    float s_r[4]; u64 bal_r[4]; bool v_r[4];
    #pragma unroll
    for (int it = 0; it < 4; ++it) {
        int c = wv + it * 4;
        s_r[it] = 0.0f; bal_r[it] = 0ull; v_r[it] = false;
        if (c < NCHUNK) {
            float x = sc_base[c * 64 + lane];
            x = fminf(fmaxf(x, -100.0f), 100.0f);
            float s = 1.0f / (1.0f + expf(-x));
            bool v = (s >= 0.75f);
            u64 bal = __ballot(v);
            s_r[it] = s; bal_r[it] = bal; v_r[it] = v;
            if (lane == 0) cnt[c] = (int)__popcll(bal);
        }
    }
    for (int t = tid; t < CAP * 6; t += 256) ((u32*)cl)[t] = 0u;
    __syncthreads();

    // ---- Phase 1b: prefix + scatter ----
    int cn[NCHUNK];
    #pragma unroll
    for (int j = 0; j < NCHUNK; ++j) cn[j] = cnt[j];
    int C = 0;
    #pragma unroll
    for (int j = 0; j < NCHUNK; ++j) C += cn[j];
    if (use_ws && tid == 0) ws[b] = C;
    if (C > CAP) return;   // uniform; fallback kernel owns this block
    #pragma unroll
    for (int it = 0; it < 4; ++it) {
        int c = wv + it * 4;
        if (c < NCHUNK && v_r[it]) {
            int base = 0;
            #pragma unroll
            for (int j = 0; j < NCHUNK; ++j) base += (j < c) ? cn[j] : 0;
            int slot = base + (int)__popcll(bal_r[it] & ((1ull << lane) - 1ull));
            keys[slot]   = ((u64)__float_as_uint(s_r[it]) << 8) | (u64)(255 - slot);
            slot_a[slot] = c * 64 + lane;
            slot_s[slot] = s_r[it];
        }
    }
    __syncthreads();

    // ---- Phase 2: rank-by-count sort (keys unique) ----
    {
        u64 myk = (tid < C) ? keys[tid] : 0ull;
        int q = 0;
        #pragma unroll 4
        for (int i = 0; i < C; ++i) q += (keys[i] > myk) ? 1 : 0;
        if (tid < C) { srt_a[q] = slot_a[tid]; det[q][16] = slot_s[tid]; }
    }
    __syncthreads();

    // ---- Phase 3: decode (one sorted row per thread) ----
    if (tid < C) {
        int a = srt_a[tid];
        const float4 an = ((const float4*)anchors)[a];
        const float4* rb = (const float4*)(raw_box + ((size_t)b * NA + a) * 16);
        float4 r0 = rb[0], r1 = rb[1], r2 = rb[2], r3 = rb[3];
        float ax = an.x, ay = an.y, aw = an.z, ah = an.w;
        float xc = r0.x / 128.0f * aw + ax;
        float yc = r0.y / 128.0f * ah + ay;
        float w  = r0.z / 128.0f * aw;
        float h  = r0.w / 128.0f * ah;
        float d0 = yc - h * 0.5f, d1 = xc - w * 0.5f;
        float d2 = yc + h * 0.5f, d3 = xc + w * 0.5f;
        det[tid][0] = d0; det[tid][1] = d1; det[tid][2] = d2; det[tid][3] = d3;
        sbox[tid] = make_float4(d0, d1, d2, d3);
        float kp[12] = {r1.x, r1.y, r1.z, r1.w,
                        r2.x, r2.y, r2.z, r2.w,
                        r3.x, r3.y, r3.z, r3.w};
        #pragma unroll
        for (int t = 0; t < 6; ++t) {
            det[tid][4 + 2 * t] = kp[2 * t]     / 128.0f * aw + ax;
            det[tid][5 + 2 * t] = kp[2 * t + 1] / 128.0f * ah + ay;
        }
    }
    __syncthreads();

    // ---- Phase 4: overlap bitmatrix, one row per thread (bit-symmetric) ----
    u64 mw0 = 0, mw1 = 0, mw2 = 0;   // stays in registers for fc later
    if (tid < C) {
        float4 sb = sbox[tid];
        float bx = sb.x, by = sb.y, bz = sb.z, bw = sb.w;
        float ar = (bz - bx) * (bw - by);   // own row = own box as "picked"
        #pragma unroll
        for (int w_ = 0; w_ < 3; ++w_) {
            int base = w_ * 64;
            int ke = C - base; if (ke > 64) ke = 64;
            u64 mm = 0, bit = 1ull;
            #pragma unroll 4
            for (int k = 0; k < ke; ++k, bit <<= 1) {
                float4 bk = sbox[base + k];
                float ak = (bk.z - bk.x) * (bk.w - bk.y);
                float i0 = fmaxf(bx, bk.x), i1 = fmaxf(by, bk.y);
                float i2 = fminf(bz, bk.z), i3 = fminf(bw, bk.w);
                float inter = (i2 - i0) * (i3 - i1);
                float qq = inter / (ar + ak - inter);  // NaN -> no bit
                if (qq > 0.3f) mm |= bit;
            }
            if (w_ == 0) mw0 = mm; else if (w_ == 1) mw1 = mm; else mw2 = mm;
        }
        mat0[tid] = mw0; mat1[tid] = mw1; mat2[tid] = mw2;
    }
    __syncthreads();

    // ---- Phase 5: wave 0 computes pick set; waves 1-3 zero-fill output ----
    if (wv == 0) {
        u64 m00 = mat0[lane],       m01 = mat1[lane],       m02 = mat2[lane];
        u64 m10 = mat0[lane + 64],  m11 = mat1[lane + 64],  m12 = mat2[lane + 64];
        u64 m20 = mat0[lane + 128], m21 = mat1[lane + 128], m22 = mat2[lane + 128];
        u64 rem0 = (C >= 64)  ? ~0ull : ((C > 0)   ? ((1ull << C) - 1)         : 0ull);
        u64 rem1 = (C >= 128) ? ~0ull : ((C > 64)  ? ((1ull << (C - 64)) - 1)  : 0ull);
        u64 rem2 = (C >= 192) ? ~0ull : ((C > 128) ? ((1ull << (C - 128)) - 1) : 0ull);
        u64 P0 = 0, P1 = 0, P2 = 0;
        int stk = CAP;

        while (rem0) {
            int i = (int)__builtin_ctzll(rem0);        // uniform -> scalar
            u64 r0 = rl64(m00, i), r1 = rl64(m01, i), r2 = rl64(m02, i);
            if (!((r0 >> i) & 1ull)) { stk = i; break; }   // degenerate: freeze
            P0 |= 1ull << i;
            rem0 &= ~r0; rem1 &= ~r1; rem2 &= ~r2;
        }
        if (stk == CAP) while (rem1) {
            int i = (int)__builtin_ctzll(rem1);
            u64 r1 = rl64(m11, i), r2 = rl64(m12, i);
            if (!((r1 >> i) & 1ull)) { stk = 64 + i; break; }
            P1 |= 1ull << i;
            rem1 &= ~r1; rem2 &= ~r2;
        }
        if (stk == CAP) while (rem2) {
            int i = (int)__builtin_ctzll(rem2);
            u64 r2 = rl64(m22, i);
            if (!((r2 >> i) & 1ull)) { stk = 128 + i; break; }
            P2 |= 1ull << i;
            rem2 &= ~r2;
        }
        if (lane == 0) { Psh[0] = P0; Psh[1] = P1; Psh[2] = P2; stuck_sh = stk; }
    } else {
        // overlapped with the (short) scan; emission overwrites rows later
        for (int t = tid - 64; t < MAXDET * 17; t += 192) out_b[t] = 0.0f;
        for (int t = tid - 64; t < MAXDET;      t += 192) flg_b[t] = 0.0f;
    }
    __syncthreads();

    const u64 P0 = Psh[0], P1 = Psh[1], P2 = Psh[2];
    const int stuck_v = stuck_sh;

    // ---- Phase 5b: parallel remover-scatter: cl[fc(k)] |= bit(k) ----
    if (tid < C) {
        u64 q0 = mw0 & P0, q1 = mw1 & P1, q2 = mw2 & P2;
        int fc = -1;
        if      (q0) fc = (int)__builtin_ctzll(q0);
        else if (q1) fc = 64  + (int)__builtin_ctzll(q1);
        else if (q2) fc = 128 + (int)__builtin_ctzll(q2);
        if (fc >= 0) atomicOr(&cl[fc][tid >> 5], 1u << (tid & 31));
    }
    __syncthreads();

    // ---- Phase 6: parallel emission by pick rank ----
    const int Pn = (int)__popcll(P0) + (int)__popcll(P1) + (int)__popcll(P2);
    bool is_pick = false;
    if (tid < C) {
        is_pick = (tid < 64)  ? ((P0 >> tid) & 1ull)
                : (tid < 128) ? ((P1 >> (tid - 64)) & 1ull)
                              : ((P2 >> (tid - 128)) & 1ull);
    }
    if (is_pick) {
        int s;
        if (tid < 64)
            s = (int)__popcll(P0 & ((tid ? ((1ull << tid) - 1) : 0ull)));
        else if (tid < 128)
            s = (int)__popcll(P0)
              + (int)__popcll(P1 & (((tid - 64) ? ((1ull << (tid - 64)) - 1) : 0ull)));
        else
            s = (int)__popcll(P0) + (int)__popcll(P1)
              + (int)__popcll(P2 & (((tid - 128) ? ((1ull << (tid - 128)) - 1) : 0ull)));

        u64 c0 = (u64)cl[tid][0] | ((u64)cl[tid][1] << 32);
        u64 c1 = (u64)cl[tid][2] | ((u64)cl[tid][3] << 32);
        u64 c2 = (u64)cl[tid][4] | ((u64)cl[tid][5] << 32);
        int n = (int)__popcll(c0) + (int)__popcll(c1) + (int)__popcll(c2);
        float* orow = out_b + s * 17;
        if (n <= 1) {
            #pragma unroll
            for (int c = 0; c < 17; ++c) orow[c] = det[tid][c];
        } else {
            float tot = 0.0f, wc[16];
            #pragma unroll
            for (int c = 0; c < 16; ++c) wc[c] = 0.0f;
            u64 m = c0;
            while (m) { int k = (int)__builtin_ctzll(m); m &= m - 1;
                float sc = det[k][16]; tot += sc;
                #pragma unroll
                for (int c = 0; c < 16; ++c) wc[c] += det[k][c] * sc; }
            m = c1;
            while (m) { int k = 64 + (int)__builtin_ctzll(m); m &= m - 1;
                float sc = det[k][16]; tot += sc;
                #pragma unroll
                for (int c = 0; c < 16; ++c) wc[c] += det[k][c] * sc; }
            m = c2;
            while (m) { int k = 128 + (int)__builtin_ctzll(m); m &= m - 1;
                float sc = det[k][16]; tot += sc;
                #pragma unroll
                for (int c = 0; c < 16; ++c) wc[c] += det[k][c] * sc; }
            float safe = (tot > 0.0f) ? tot : 1.0f;
            #pragma unroll
            for (int c = 0; c < 16; ++c) orow[c] = wc[c] / safe;
            orow[16] = tot / (float)n;
        }
        flg_b[s] = 1.0f;
    }
    // frozen-tail replication for the (unreachable) degenerate case
    if (stuck_v < CAP) {
        for (int s2 = Pn + tid; s2 < MAXDET; s2 += 256) {
            float* orow = out_b + s2 * 17;
            #pragma unroll
            for (int c = 0; c < 17; ++c) orow[c] = det[stuck_v][c];
            flg_b[s2] = 1.0f;
        }
    }
}

// ---------------- fallback: C > 192 (statistically unreachable) ------------
__global__ __launch_bounds__(64, 1) void nms_fallback(
    const float* __restrict__ raw_box,
    const float* __restrict__ raw_score,
    const float* __restrict__ anchors,
    float* __restrict__ out,
    float* __restrict__ flags,
    const int* __restrict__ ws, int use_ws)
{
    const int b    = blockIdx.x;
    const int lane = threadIdx.x;
    if (use_ws && ws[b] <= CAP) return;   // cheap early-out

    __shared__ float det[NA][17];
    __shared__ int   cand_a[NA];

    int C = 0;
    const float* sc_base = raw_score + (size_t)b * NA;
    #pragma unroll
    for (int c = 0; c < NA / 64; ++c) {
        int a = c * 64 + lane;
        float x = sc_base[a];
        x = fminf(fmaxf(x, -100.0f), 100.0f);
        float s = 1.0f / (1.0f + expf(-x));
        bool v = (s >= 0.75f);
        u64 bal = __ballot(v);
        if (v) {
            int slot = C + (int)__popcll(bal & ((1ull << lane) - 1ull));
            cand_a[slot]  = a;
            det[slot][16] = s;
        }
        C += (int)__popcll(bal);
    }
    if (C <= CAP) return;   // fast kernel owns this block
    __syncthreads();

    for (int k = lane; k < C; k += 64) {
        int a = cand_a[k];
        const float4 an = ((const float4*)anchors)[a];
        const float4* rb = (const float4*)(raw_box + ((size_t)b * NA + a) * 16);
        float4 r0 = rb[0], r1 = rb[1], r2 = rb[2], r3 = rb[3];
        float ax = an.x, ay = an.y, aw = an.z, ah = an.w;
        float xc = r0.x / 128.0f * aw + ax;
        float yc = r0.y / 128.0f * ah + ay;
        float w  = r0.z / 128.0f * aw;
        float h  = r0.w / 128.0f * ah;
        det[k][0] = yc - h * 0.5f;
        det[k][1] = xc - w * 0.5f;
        det[k][2] = yc + h * 0.5f;
        det[k][3] = xc + w * 0.5f;
        float kp[12] = {r1.x, r1.y, r1.z, r1.w,
                        r2.x, r2.y, r2.z, r2.w,
                        r3.x, r3.y, r3.z, r3.w};
        #pragma unroll
        for (int t = 0; t < 6; ++t) {
            det[k][4 + 2 * t] = kp[2 * t]     / 128.0f * aw + ax;
            det[k][5 + 2 * t] = kp[2 * t + 1] / 128.0f * ah + ay;
        }
    }
    __syncthreads();

    const int nj = (C + 63) >> 6;
    unsigned int rem = 0;
    for (int j = 0; j < nj; ++j)
        if (lane + (j << 6) < C) rem |= (1u << j);

    float* out_b = out   + (size_t)b * MAXDET * 17;
    float* flg_b = flags + (size_t)b * MAXDET;

    int step = 0;
    for (; step < MAXDET; ++step) {
        u64 best = 0;
        for (int j = 0; j < nj; ++j) {
            if (rem & (1u << j)) {
                int k = lane + (j << 6);
                u64 key = ((u64)__float_as_uint(det[k][16]) << 10) |
                          (u64)(1023 - k);
                if (key > best) best = key;
            }
        }
        #pragma unroll
        for (int off = 32; off; off >>= 1) {
            u64 o = __shfl_xor(best, off);
            if (o > best) best = o;
        }
        if (best == 0) break;
        int idx = 1023 - (int)(best & 1023ull);

        float bx0 = det[idx][0], bx1 = det[idx][1];
        float bx2 = det[idx][2], bx3 = det[idx][3];
        float areaA = (bx2 - bx0) * (bx3 - bx1);

        unsigned int ov = 0;
        for (int j = 0; j < nj; ++j) {
            if (rem & (1u << j)) {
                int k = lane + (j << 6);
                float c0 = det[k][0], c1 = det[k][1];
                float c2 = det[k][2], c3 = det[k][3];
                float i0 = fmaxf(bx0, c0);
                float i1 = fmaxf(bx1, c1);
                float i2 = fminf(bx2, c2);
                float i3 = fminf(bx3, c3);
                float inter = (i2 - i0) * (i3 - i1);
                float areaB = (c2 - c0) * (c3 - c1);
                float q = inter / (areaA + areaB - inter);
                if (q > 0.3f) ov |= (1u << j);
            }
        }
        rem &= ~ov;

        int n = 0;
        for (int j = 0; j < nj; ++j)
            n += (int)__popcll(__ballot((ov >> j) & 1u));

        if (n <= 1) {
            if (lane < 17) out_b[step * 17 + lane] = det[idx][lane];
            if (lane == 17) flg_b[step] = 1.0f;
        } else {
            float tot = 0.0f, wc[16];
            #pragma unroll
            for (int c = 0; c < 16; ++c) wc[c] = 0.0f;
            for (int j = 0; j < nj; ++j) {
                if (ov & (1u << j)) {
                    int k = lane + (j << 6);
                    float s = det[k][16];
                    tot += s;
                    #pragma unroll
                    for (int c = 0; c < 16; ++c) wc[c] += det[k][c] * s;
                }
            }
            #pragma unroll
            for (int off = 32; off; off >>= 1) {
                tot += __shfl_xor(tot, off);
                #pragma unroll
                for (int c = 0; c < 16; ++c) wc[c] += __shfl_xor(wc[c], off);
            }
            if (lane == 0) {
                float safe = (tot > 0.0f) ? tot : 1.0f;
                #pragma unroll
                for (int c = 0; c < 16; ++c) out_b[step * 17 + c] = wc[c] / safe;
                out_b[step * 17 + 16] = tot / (float)n;
                flg_b[step] = 1.0f;
            }
        }
    }

    for (int t = step * 17 + lane; t < MAXDET * 17; t += 64) out_b[t] = 0.0f;
    for (int t = step + lane;      t < MAXDET;      t += 64) flg_b[t] = 0.0f;
}

extern "C" void kernel_launch(void* const* d_in, const int* in_sizes, int n_in,
                              void* d_out, int out_size, void* d_ws, size_t ws_size,
                              hipStream_t stream) {
    const float* raw_box   = (const float*)d_in[0];
    const float* raw_score = (const float*)d_in[1];
    const float* anchors   = (const float*)d_in[2];
    float* out   = (float*)d_out;
    float* flags = out + (size_t)NBATCH * MAXDET * 17;
    int use_ws = (ws_size >= NBATCH * sizeof(int)) ? 1 : 0;
    nms_fast    <<<NBATCH, 256, 0, stream>>>(raw_box, raw_score, anchors, out, flags,
                                             (int*)d_ws, use_ws);
    nms_fallback<<<NBATCH, 64, 0, stream>>>(raw_box, raw_score, anchors, out, flags,
                                            (const int*)d_ws, use_ws);
}

// Round 7
// 37.820 us; speedup vs baseline: 1.8427x; 1.1094x over previous
//
#include <hip/hip_runtime.h>
#include <math.h>

#pragma clang fp contract(off)

#define NA      896
#define MAXDET  256
#define NBATCH  512
#define CAP     192
#define NCHUNK  14

typedef unsigned long long u64;
typedef unsigned int u32;

__device__ __forceinline__ u64 rl64(u64 v, int l) {
    u32 lo = __builtin_amdgcn_readlane((u32)v, l);
    u32 hi = __builtin_amdgcn_readlane((u32)(v >> 32), l);
    return ((u64)hi << 32) | (u64)lo;
}

// ---------------- fast path: C <= 192, one batch per 8-wave block ----------
// R6 algorithm (pick-set scan + parallel fc-scatter clusters), restructured
// for 512 threads: finer matrix split (one row-word per thread), decode
// gather overlapped under the sort-rank loop, 16 waves/CU.
__global__ __launch_bounds__(512, 2) void nms_fast(
    const float* __restrict__ raw_box,
    const float* __restrict__ raw_score,
    const float* __restrict__ anchors,
    float* __restrict__ out,
    float* __restrict__ flags,
    int* __restrict__ ws, int use_ws)
{
    __shared__ float  det[CAP][17];
    __shared__ float4 sbox[CAP];
    __shared__ u64    keys[CAP];
    __shared__ int    slot_a[CAP];
    __shared__ float  slot_s[CAP];
    __shared__ u64    mat0[CAP], mat1[CAP], mat2[CAP];
    __shared__ u32    cl[CAP][6];
    __shared__ u64    Psh[3];
    __shared__ int    stuck_sh;
    __shared__ int    cnt[NCHUNK];

    const int b    = blockIdx.x;
    const int tid  = threadIdx.x;
    const int lane = tid & 63;
    const int wv   = tid >> 6;          // 0..7

    const float* sc_base = raw_score + (size_t)b * NA;
    float* out_b = out   + (size_t)b * MAXDET * 17;
    float* flg_b = flags + (size_t)b * MAXDET;

    // ---- Phase 1: scores + per-chunk ballots (chunk c = wv + 8r); cl init ----
    float s_r[2]; u64 bal_r[2]; bool v_r[2];
    #pragma unroll
    for (int r = 0; r < 2; ++r) {
        int c = wv + r * 8;
        s_r[r] = 0.0f; bal_r[r] = 0ull; v_r[r] = false;
        if (c < NCHUNK) {
            float x = sc_base[c * 64 + lane];
            x = fminf(fmaxf(x, -100.0f), 100.0f);
            float s = 1.0f / (1.0f + expf(-x));
            bool v = (s >= 0.75f);
            u64 bal = __ballot(v);
            s_r[r] = s; bal_r[r] = bal; v_r[r] = v;
            if (lane == 0) cnt[c] = (int)__popcll(bal);
        }
    }
    for (int t = tid; t < CAP * 6; t += 512) ((u32*)cl)[t] = 0u;
    __syncthreads();

    // ---- Phase 2: prefix (registers) + scatter ----
    int cn[NCHUNK];
    #pragma unroll
    for (int j = 0; j < NCHUNK; ++j) cn[j] = cnt[j];
    int C = 0;
    #pragma unroll
    for (int j = 0; j < NCHUNK; ++j) C += cn[j];
    if (use_ws && tid == 0) ws[b] = C;
    if (C > CAP) return;   // uniform; fallback kernel owns this block
    #pragma unroll
    for (int r = 0; r < 2; ++r) {
        int c = wv + r * 8;
        if (c < NCHUNK && v_r[r]) {
            int base = 0;
            #pragma unroll
            for (int j = 0; j < NCHUNK; ++j) base += (j < c) ? cn[j] : 0;
            int slot = base + (int)__popcll(bal_r[r] & ((1ull << lane) - 1ull));
            keys[slot]   = ((u64)__float_as_uint(s_r[r]) << 8) | (u64)(255 - slot);
            slot_a[slot] = c * 64 + lane;
            slot_s[slot] = s_r[r];
        }
    }
    __syncthreads();

    // ---- Phase 3: gather (issued early) + rank loop + decode to det[q] ----
    if (tid < C) {
        int a = slot_a[tid];
        float s = slot_s[tid];
        // issue HBM loads now; they complete under the rank loop below
        const float4 an = ((const float4*)anchors)[a];
        const float4* rb = (const float4*)(raw_box + ((size_t)b * NA + a) * 16);
        float4 r0 = rb[0], r1 = rb[1], r2 = rb[2], r3 = rb[3];

        u64 myk = keys[tid];
        int q = 0;
        #pragma unroll 8
        for (int i = 0; i < C; ++i) q += (keys[i] > myk) ? 1 : 0;

        float ax = an.x, ay = an.y, aw = an.z, ah = an.w;
        float xc = r0.x / 128.0f * aw + ax;
        float yc = r0.y / 128.0f * ah + ay;
        float w  = r0.z / 128.0f * aw;
        float h  = r0.w / 128.0f * ah;
        float d0 = yc - h * 0.5f, d1 = xc - w * 0.5f;
        float d2 = yc + h * 0.5f, d3 = xc + w * 0.5f;
        det[q][0] = d0; det[q][1] = d1; det[q][2] = d2; det[q][3] = d3;
        det[q][16] = s;
        sbox[q] = make_float4(d0, d1, d2, d3);
        float kp[12] = {r1.x, r1.y, r1.z, r1.w,
                        r2.x, r2.y, r2.z, r2.w,
                        r3.x, r3.y, r3.z, r3.w};
        #pragma unroll
        for (int t = 0; t < 6; ++t) {
            det[q][4 + 2 * t] = kp[2 * t]     / 128.0f * aw + ax;
            det[q][5 + 2 * t] = kp[2 * t + 1] / 128.0f * ah + ay;
        }
    }
    __syncthreads();

    // ---- Phase 4: overlap bitmatrix, one (row, word) unit per thread ----
    {
        int row  = (tid < 192) ? tid : (tid < 384 ? tid - 192 : tid - 384);
        int word = (tid < 192) ? 0   : (tid < 384 ? 1         : 2);
        int base = word << 6;
        int ke = C - base; if (ke > 64) ke = 64;
        u64 mm = 0;
        if (row < C && ke > 0) {
            float4 sb = sbox[row];
            float bx = sb.x, by = sb.y, bz = sb.z, bw = sb.w;
            float ar = (bz - bx) * (bw - by);
            u64 bit = 1ull;
            #pragma unroll 4
            for (int k = 0; k < ke; ++k, bit <<= 1) {
                float4 bk = sbox[base + k];
                float ak = (bk.z - bk.x) * (bk.w - bk.y);
                float i0 = fmaxf(bx, bk.x), i1 = fmaxf(by, bk.y);
                float i2 = fminf(bz, bk.z), i3 = fminf(bw, bk.w);
                float inter = (i2 - i0) * (i3 - i1);
                float qq = inter / (ar + ak - inter);  // NaN -> no bit
                if (qq > 0.3f) mm |= bit;
            }
        }
        if (word == 0) mat0[row] = mm;
        else if (word == 1) mat1[row] = mm;
        else mat2[row] = mm;
    }
    if (tid < 64) {   // second unit: rows 128..191, word 2
        int row = 128 + tid;
        int ke = C - 128; if (ke > 64) ke = 64;
        u64 mm = 0;
        if (row < C && ke > 0) {
            float4 sb = sbox[row];
            float bx = sb.x, by = sb.y, bz = sb.z, bw = sb.w;
            float ar = (bz - bx) * (bw - by);
            u64 bit = 1ull;
            #pragma unroll 4
            for (int k = 0; k < ke; ++k, bit <<= 1) {
                float4 bk = sbox[128 + k];
                float ak = (bk.z - bk.x) * (bk.w - bk.y);
                float i0 = fmaxf(bx, bk.x), i1 = fmaxf(by, bk.y);
                float i2 = fminf(bz, bk.z), i3 = fminf(bw, bk.w);
                float inter = (i2 - i0) * (i3 - i1);
                float qq = inter / (ar + ak - inter);
                if (qq > 0.3f) mm |= bit;
            }
        }
        mat2[row] = mm;
    }
    __syncthreads();

    // ---- Phase 5: wave 0 pick-set scan; waves 1-7 zero-fill output ----
    if (wv == 0) {
        u64 m00 = mat0[lane],       m01 = mat1[lane],       m02 = mat2[lane];
        u64 m10 = mat0[lane + 64],  m11 = mat1[lane + 64],  m12 = mat2[lane + 64];
        u64 m20 = mat0[lane + 128], m21 = mat1[lane + 128], m22 = mat2[lane + 128];
        u64 rem0 = (C >= 64)  ? ~0ull : ((C > 0)   ? ((1ull << C) - 1)         : 0ull);
        u64 rem1 = (C >= 128) ? ~0ull : ((C > 64)  ? ((1ull << (C - 64)) - 1)  : 0ull);
        u64 rem2 = (C >= 192) ? ~0ull : ((C > 128) ? ((1ull << (C - 128)) - 1) : 0ull);
        u64 P0 = 0, P1 = 0, P2 = 0;
        int stk = CAP;

        while (rem0) {
            int i = (int)__builtin_ctzll(rem0);        // uniform -> scalar
            u64 r0 = rl64(m00, i), r1 = rl64(m01, i), r2 = rl64(m02, i);
            if (!((r0 >> i) & 1ull)) { stk = i; break; }   // degenerate: freeze
            P0 |= 1ull << i;
            rem0 &= ~r0; rem1 &= ~r1; rem2 &= ~r2;
        }
        if (stk == CAP) while (rem1) {
            int i = (int)__builtin_ctzll(rem1);
            u64 r1 = rl64(m11, i), r2 = rl64(m12, i);
            if (!((r1 >> i) & 1ull)) { stk = 64 + i; break; }
            P1 |= 1ull << i;
            rem1 &= ~r1; rem2 &= ~r2;
        }
        if (stk == CAP) while (rem2) {
            int i = (int)__builtin_ctzll(rem2);
            u64 r2 = rl64(m22, i);
            if (!((r2 >> i) & 1ull)) { stk = 128 + i; break; }
            P2 |= 1ull << i;
            rem2 &= ~r2;
        }
        if (lane == 0) { Psh[0] = P0; Psh[1] = P1; Psh[2] = P2; stuck_sh = stk; }
    } else {
        for (int t = tid - 64; t < MAXDET * 17; t += 448) out_b[t] = 0.0f;
        for (int t = tid - 64; t < MAXDET;      t += 448) flg_b[t] = 0.0f;
    }
    __syncthreads();

    const u64 P0 = Psh[0], P1 = Psh[1], P2 = Psh[2];
    const int stuck_v = stuck_sh;

    // ---- Phase 6: parallel remover-scatter: cl[fc(k)] |= bit(k) ----
    if (tid < C) {
        u64 q0 = mat0[tid] & P0, q1 = mat1[tid] & P1, q2 = mat2[tid] & P2;
        int fc = -1;
        if      (q0) fc = (int)__builtin_ctzll(q0);
        else if (q1) fc = 64  + (int)__builtin_ctzll(q1);
        else if (q2) fc = 128 + (int)__builtin_ctzll(q2);
        if (fc >= 0) atomicOr(&cl[fc][tid >> 5], 1u << (tid & 31));
    }
    __syncthreads();

    // ---- Phase 7: parallel emission by pick rank ----
    const int Pn = (int)__popcll(P0) + (int)__popcll(P1) + (int)__popcll(P2);
    bool is_pick = false;
    if (tid < C) {
        is_pick = (tid < 64)  ? ((P0 >> tid) & 1ull)
                : (tid < 128) ? ((P1 >> (tid - 64)) & 1ull)
                              : ((P2 >> (tid - 128)) & 1ull);
    }
    if (is_pick) {
        int s;
        if (tid < 64)
            s = (int)__popcll(P0 & ((tid ? ((1ull << tid) - 1) : 0ull)));
        else if (tid < 128)
            s = (int)__popcll(P0)
              + (int)__popcll(P1 & (((tid - 64) ? ((1ull << (tid - 64)) - 1) : 0ull)));
        else
            s = (int)__popcll(P0) + (int)__popcll(P1)
              + (int)__popcll(P2 & (((tid - 128) ? ((1ull << (tid - 128)) - 1) : 0ull)));

        u64 c0 = (u64)cl[tid][0] | ((u64)cl[tid][1] << 32);
        u64 c1 = (u64)cl[tid][2] | ((u64)cl[tid][3] << 32);
        u64 c2 = (u64)cl[tid][4] | ((u64)cl[tid][5] << 32);
        int n = (int)__popcll(c0) + (int)__popcll(c1) + (int)__popcll(c2);
        float* orow = out_b + s * 17;
        if (n <= 1) {
            #pragma unroll
            for (int c = 0; c < 17; ++c) orow[c] = det[tid][c];
        } else {
            float tot = 0.0f, wc[16];
            #pragma unroll
            for (int c = 0; c < 16; ++c) wc[c] = 0.0f;
            u64 m = c0;
            while (m) { int k = (int)__builtin_ctzll(m); m &= m - 1;
                float sc = det[k][16]; tot += sc;
                #pragma unroll
                for (int c = 0; c < 16; ++c) wc[c] += det[k][c] * sc; }
            m = c1;
            while (m) { int k = 64 + (int)__builtin_ctzll(m); m &= m - 1;
                float sc = det[k][16]; tot += sc;
                #pragma unroll
                for (int c = 0; c < 16; ++c) wc[c] += det[k][c] * sc; }
            m = c2;
            while (m) { int k = 128 + (int)__builtin_ctzll(m); m &= m - 1;
                float sc = det[k][16]; tot += sc;
                #pragma unroll
                for (int c = 0; c < 16; ++c) wc[c] += det[k][c] * sc; }
            float safe = (tot > 0.0f) ? tot : 1.0f;
            #pragma unroll
            for (int c = 0; c < 16; ++c) orow[c] = wc[c] / safe;
            orow[16] = tot / (float)n;
        }
        flg_b[s] = 1.0f;
    }
    // frozen-tail replication for the (unreachable) degenerate case
    if (stuck_v < CAP) {
        for (int s2 = Pn + tid; s2 < MAXDET; s2 += 512) {
            float* orow = out_b + s2 * 17;
            #pragma unroll
            for (int c = 0; c < 17; ++c) orow[c] = det[stuck_v][c];
            flg_b[s2] = 1.0f;
        }
    }
}

// ---------------- fallback: C > 192 (statistically unreachable) ------------
__global__ __launch_bounds__(64, 1) void nms_fallback(
    const float* __restrict__ raw_box,
    const float* __restrict__ raw_score,
    const float* __restrict__ anchors,
    float* __restrict__ out,
    float* __restrict__ flags,
    const int* __restrict__ ws, int use_ws)
{
    const int b    = blockIdx.x;
    const int lane = threadIdx.x;
    if (use_ws && ws[b] <= CAP) return;   // cheap early-out

    __shared__ float det[NA][17];
    __shared__ int   cand_a[NA];

    int C = 0;
    const float* sc_base = raw_score + (size_t)b * NA;
    #pragma unroll
    for (int c = 0; c < NA / 64; ++c) {
        int a = c * 64 + lane;
        float x = sc_base[a];
        x = fminf(fmaxf(x, -100.0f), 100.0f);
        float s = 1.0f / (1.0f + expf(-x));
        bool v = (s >= 0.75f);
        u64 bal = __ballot(v);
        if (v) {
            int slot = C + (int)__popcll(bal & ((1ull << lane) - 1ull));
            cand_a[slot]  = a;
            det[slot][16] = s;
        }
        C += (int)__popcll(bal);
    }
    if (C <= CAP) return;   // fast kernel owns this block
    __syncthreads();

    for (int k = lane; k < C; k += 64) {
        int a = cand_a[k];
        const float4 an = ((const float4*)anchors)[a];
        const float4* rb = (const float4*)(raw_box + ((size_t)b * NA + a) * 16);
        float4 r0 = rb[0], r1 = rb[1], r2 = rb[2], r3 = rb[3];
        float ax = an.x, ay = an.y, aw = an.z, ah = an.w;
        float xc = r0.x / 128.0f * aw + ax;
        float yc = r0.y / 128.0f * ah + ay;
        float w  = r0.z / 128.0f * aw;
        float h  = r0.w / 128.0f * ah;
        det[k][0] = yc - h * 0.5f;
        det[k][1] = xc - w * 0.5f;
        det[k][2] = yc + h * 0.5f;
        det[k][3] = xc + w * 0.5f;
        float kp[12] = {r1.x, r1.y, r1.z, r1.w,
                        r2.x, r2.y, r2.z, r2.w,
                        r3.x, r3.y, r3.z, r3.w};
        #pragma unroll
        for (int t = 0; t < 6; ++t) {
            det[k][4 + 2 * t] = kp[2 * t]     / 128.0f * aw + ax;
            det[k][5 + 2 * t] = kp[2 * t + 1] / 128.0f * ah + ay;
        }
    }
    __syncthreads();

    const int nj = (C + 63) >> 6;
    unsigned int rem = 0;
    for (int j = 0; j < nj; ++j)
        if (lane + (j << 6) < C) rem |= (1u << j);

    float* out_b = out   + (size_t)b * MAXDET * 17;
    float* flg_b = flags + (size_t)b * MAXDET;

    int step = 0;
    for (; step < MAXDET; ++step) {
        u64 best = 0;
        for (int j = 0; j < nj; ++j) {
            if (rem & (1u << j)) {
                int k = lane + (j << 6);
                u64 key = ((u64)__float_as_uint(det[k][16]) << 10) |
                          (u64)(1023 - k);
                if (key > best) best = key;
            }
        }
        #pragma unroll
        for (int off = 32; off; off >>= 1) {
            u64 o = __shfl_xor(best, off);
            if (o > best) best = o;
        }
        if (best == 0) break;
        int idx = 1023 - (int)(best & 1023ull);

        float bx0 = det[idx][0], bx1 = det[idx][1];
        float bx2 = det[idx][2], bx3 = det[idx][3];
        float areaA = (bx2 - bx0) * (bx3 - bx1);

        unsigned int ov = 0;
        for (int j = 0; j < nj; ++j) {
            if (rem & (1u << j)) {
                int k = lane + (j << 6);
                float c0 = det[k][0], c1 = det[k][1];
                float c2 = det[k][2], c3 = det[k][3];
                float i0 = fmaxf(bx0, c0);
                float i1 = fmaxf(bx1, c1);
                float i2 = fminf(bx2, c2);
                float i3 = fminf(bx3, c3);
                float inter = (i2 - i0) * (i3 - i1);
                float areaB = (c2 - c0) * (c3 - c1);
                float q = inter / (areaA + areaB - inter);
                if (q > 0.3f) ov |= (1u << j);
            }
        }
        rem &= ~ov;

        int n = 0;
        for (int j = 0; j < nj; ++j)
            n += (int)__popcll(__ballot((ov >> j) & 1u));

        if (n <= 1) {
            if (lane < 17) out_b[step * 17 + lane] = det[idx][lane];
            if (lane == 17) flg_b[step] = 1.0f;
        } else {
            float tot = 0.0f, wc[16];
            #pragma unroll
            for (int c = 0; c < 16; ++c) wc[c] = 0.0f;
            for (int j = 0; j < nj; ++j) {
                if (ov & (1u << j)) {
                    int k = lane + (j << 6);
                    float s = det[k][16];
                    tot += s;
                    #pragma unroll
                    for (int c = 0; c < 16; ++c) wc[c] += det[k][c] * s;
                }
            }
            #pragma unroll
            for (int off = 32; off; off >>= 1) {
                tot += __shfl_xor(tot, off);
                #pragma unroll
                for (int c = 0; c < 16; ++c) wc[c] += __shfl_xor(wc[c], off);
            }
            if (lane == 0) {
                float safe = (tot > 0.0f) ? tot : 1.0f;
                #pragma unroll
                for (int c = 0; c < 16; ++c) out_b[step * 17 + c] = wc[c] / safe;
                out_b[step * 17 + 16] = tot / (float)n;
                flg_b[step] = 1.0f;
            }
        }
    }

    for (int t = step * 17 + lane; t < MAXDET * 17; t += 64) out_b[t] = 0.0f;
    for (int t = step + lane;      t < MAXDET;      t += 64) flg_b[t] = 0.0f;
}

extern "C" void kernel_launch(void* const* d_in, const int* in_sizes, int n_in,
                              void* d_out, int out_size, void* d_ws, size_t ws_size,
                              hipStream_t stream) {
    const float* raw_box   = (const float*)d_in[0];
    const float* raw_score = (const float*)d_in[1];
    const float* anchors   = (const float*)d_in[2];
    float* out   = (float*)d_out;
    float* flags = out + (size_t)NBATCH * MAXDET * 17;
    int use_ws = (ws_size >= NBATCH * sizeof(int)) ? 1 : 0;
    nms_fast    <<<NBATCH, 512, 0, stream>>>(raw_box, raw_score, anchors, out, flags,
                                             (int*)d_ws, use_ws);
    nms_fallback<<<NBATCH, 64, 0, stream>>>(raw_box, raw_score, anchors, out, flags,
                                            (const int*)d_ws, use_ws);
}

// Round 8
// 32.054 us; speedup vs baseline: 2.1742x; 1.1799x over previous
//
#include <hip/hip_runtime.h>
#include <math.h>

#pragma clang fp contract(off)

#define NA      896
#define MAXDET  256
#define NBATCH  512
#define CAP     192
#define NCHUNK  14

typedef unsigned long long u64;
typedef unsigned int u32;

__device__ __forceinline__ u64 rl64(u64 v, int l) {
    u32 lo = __builtin_amdgcn_readlane((u32)v, l);
    u32 hi = __builtin_amdgcn_readlane((u32)(v >> 32), l);
    return ((u64)hi << 32) | (u64)lo;
}

struct FastSh {                 // ~28.4 KB
    float  det[CAP][17];
    float4 sbox[CAP];
    u64    keys[CAP];
    int    slot_a[CAP];
    float  slot_s[CAP];
    u32    mat32[CAP][6];
    u32    cl[CAP][6];
};
struct SlowSh {                 // ~18 KB (correctness-only path, C > CAP)
    float  score[NA];
    float4 box[NA];
    u64    remw[NCHUNK];
};
union ShU { FastSh f; SlowSh s; };

// One batch per 8-wave block. Sorted-candidate pick-set scan (wave 0) +
// parallel fc-scatter cluster recovery + rank-ordered emission. C > CAP
// (statistically unreachable) handled inline via global-scratch slow path.
__global__ __launch_bounds__(512, 4) void nms_kernel(
    const float* __restrict__ raw_box,
    const float* __restrict__ raw_score,
    const float* __restrict__ anchors,
    float* __restrict__ out,
    float* __restrict__ flags,
    float* __restrict__ gws, int has_ws)
{
    __shared__ ShU sh;
    __shared__ u64 Psh[3];
    __shared__ int stuck_sh;
    __shared__ int Ccnt;

    const int b    = blockIdx.x;
    const int tid  = threadIdx.x;
    const int lane = tid & 63;
    const int wv   = tid >> 6;

    const float* sc_base = raw_score + (size_t)b * NA;
    float* out_b = out   + (size_t)b * MAXDET * 17;
    float* flg_b = flags + (size_t)b * MAXDET;

    if (tid == 0) Ccnt = 0;
    __syncthreads();

    // ---- Phase 1: scores + ballot compaction (order-free; anchor tiebreak
    //      lives in the key, so slot order is irrelevant) ----
    #pragma unroll
    for (int r = 0; r < 2; ++r) {
        int c = wv + r * 8;
        if (c < NCHUNK) {
            int a = c * 64 + lane;
            float x = sc_base[a];
            x = fminf(fmaxf(x, -100.0f), 100.0f);
            float s = 1.0f / (1.0f + expf(-x));
            bool v = (s >= 0.75f);
            u64 bal = __ballot(v);
            int np = (int)__popcll(bal);
            int base = 0;
            if (lane == 0 && np) base = atomicAdd(&Ccnt, np);
            base = __shfl(base, 0);
            if (v) {
                int slot = base + (int)__popcll(bal & ((1ull << lane) - 1ull));
                if (slot < CAP) {
                    sh.f.keys[slot]   = ((u64)__float_as_uint(s) << 10) | (u64)(1023 - a);
                    sh.f.slot_a[slot] = a;
                    sh.f.slot_s[slot] = s;
                }
            }
        }
    }
    __syncthreads();
    const int C = Ccnt;

    if (C > CAP) {
        // ================= slow path: correctness-only =================
        if (!has_ws) {
            for (int t = tid; t < MAXDET * 17; t += 512) out_b[t] = 0.0f;
            for (int t = tid; t < MAXDET;      t += 512) flg_b[t] = 0.0f;
            return;
        }
        float* gdet = gws + (size_t)b * NA * 17;
        for (int a0 = tid; a0 < NA; a0 += 512) {
            float x = sc_base[a0];
            x = fminf(fmaxf(x, -100.0f), 100.0f);
            float s = 1.0f / (1.0f + expf(-x));
            const float4 an = ((const float4*)anchors)[a0];
            const float4* rb = (const float4*)(raw_box + ((size_t)b * NA + a0) * 16);
            float4 r0 = rb[0], r1 = rb[1], r2 = rb[2], r3 = rb[3];
            float ax = an.x, ay = an.y, aw = an.z, ah = an.w;
            float xc = r0.x / 128.0f * aw + ax;
            float yc = r0.y / 128.0f * ah + ay;
            float w  = r0.z / 128.0f * aw;
            float h  = r0.w / 128.0f * ah;
            float d0 = yc - h * 0.5f, d1 = xc - w * 0.5f;
            float d2 = yc + h * 0.5f, d3 = xc + w * 0.5f;
            sh.s.score[a0] = s;
            sh.s.box[a0]   = make_float4(d0, d1, d2, d3);
            float* gr = gdet + (size_t)a0 * 17;
            gr[0] = d0; gr[1] = d1; gr[2] = d2; gr[3] = d3;
            float kp[12] = {r1.x, r1.y, r1.z, r1.w,
                            r2.x, r2.y, r2.z, r2.w,
                            r3.x, r3.y, r3.z, r3.w};
            #pragma unroll
            for (int t = 0; t < 6; ++t) {
                gr[4 + 2 * t] = kp[2 * t]     / 128.0f * aw + ax;
                gr[5 + 2 * t] = kp[2 * t + 1] / 128.0f * ah + ay;
            }
            gr[16] = s;
            u64 bal = __ballot(s >= 0.75f);
            if (lane == 0) sh.s.remw[a0 >> 6] = bal;
        }
        __syncthreads();
        if (wv == 0) {
            int step = 0;
            for (; step < MAXDET; ++step) {
                u64 best = 0;
                for (int c = 0; c < NCHUNK; ++c) {
                    if ((sh.s.remw[c] >> lane) & 1ull) {
                        int a = c * 64 + lane;
                        u64 key = ((u64)__float_as_uint(sh.s.score[a]) << 10)
                                | (u64)(1023 - a);
                        if (key > best) best = key;
                    }
                }
                #pragma unroll
                for (int off = 32; off; off >>= 1) {
                    u64 o = __shfl_xor(best, off);
                    if (o > best) best = o;
                }
                if (best == 0) break;
                int idx = 1023 - (int)(best & 1023ull);
                float4 bb = sh.s.box[idx];
                float areaA = (bb.z - bb.x) * (bb.w - bb.y);
                u32 ov = 0; int n = 0;
                for (int c = 0; c < NCHUNK; ++c) {
                    bool o = false;
                    if ((sh.s.remw[c] >> lane) & 1ull) {
                        int a = c * 64 + lane;
                        float4 cb = sh.s.box[a];
                        float i0 = fmaxf(bb.x, cb.x), i1 = fmaxf(bb.y, cb.y);
                        float i2 = fminf(bb.z, cb.z), i3 = fminf(bb.w, cb.w);
                        float inter = (i2 - i0) * (i3 - i1);
                        float areaB = (cb.z - cb.x) * (cb.w - cb.y);
                        float q = inter / (areaA + areaB - inter);
                        o = (q > 0.3f);
                    }
                    u64 balc = __ballot(o);
                    if (o) ov |= 1u << c;
                    n += (int)__popcll(balc);
                    if (lane == 0) sh.s.remw[c] &= ~balc;
                }
                if (n <= 1) {
                    if (lane < 17) out_b[step * 17 + lane] = gdet[(size_t)idx * 17 + lane];
                    if (lane == 17) flg_b[step] = 1.0f;
                } else {
                    float tot = 0.0f, wcv[16];
                    #pragma unroll
                    for (int j = 0; j < 16; ++j) wcv[j] = 0.0f;
                    for (int c = 0; c < NCHUNK; ++c) {
                        if ((ov >> c) & 1u) {
                            int a = c * 64 + lane;
                            float s2 = sh.s.score[a]; tot += s2;
                            #pragma unroll
                            for (int j = 0; j < 16; ++j)
                                wcv[j] += gdet[(size_t)a * 17 + j] * s2;
                        }
                    }
                    #pragma unroll
                    for (int off = 32; off; off >>= 1) {
                        tot += __shfl_xor(tot, off);
                        #pragma unroll
                        for (int j = 0; j < 16; ++j) wcv[j] += __shfl_xor(wcv[j], off);
                    }
                    if (lane == 0) {
                        float safe = (tot > 0.0f) ? tot : 1.0f;
                        #pragma unroll
                        for (int j = 0; j < 16; ++j) out_b[step * 17 + j] = wcv[j] / safe;
                        out_b[step * 17 + 16] = tot / (float)n;
                        flg_b[step] = 1.0f;
                    }
                }
            }
            for (int t = step * 17 + lane; t < MAXDET * 17; t += 64) out_b[t] = 0.0f;
            for (int t = step + lane;      t < MAXDET;      t += 64) flg_b[t] = 0.0f;
        }
        return;
        // ===============================================================
    }

    // ---- Phase 2: fused rank (rank-by-count over unique keys) + decode ----
    if (tid < C) {
        int a = sh.f.slot_a[tid];
        float s = sh.f.slot_s[tid];
        const float4 an = ((const float4*)anchors)[a];           // issued early:
        const float4* rb = (const float4*)(raw_box + ((size_t)b * NA + a) * 16);
        float4 r0 = rb[0], r1 = rb[1], r2 = rb[2], r3 = rb[3];   // hides under rank loop
        u64 myk = sh.f.keys[tid];
        int q = 0;
        #pragma unroll 8
        for (int i = 0; i < C; ++i) q += (sh.f.keys[i] > myk) ? 1 : 0;
        float ax = an.x, ay = an.y, aw = an.z, ah = an.w;
        float xc = r0.x / 128.0f * aw + ax;
        float yc = r0.y / 128.0f * ah + ay;
        float w  = r0.z / 128.0f * aw;
        float h  = r0.w / 128.0f * ah;
        float d0 = yc - h * 0.5f, d1 = xc - w * 0.5f;
        float d2 = yc + h * 0.5f, d3 = xc + w * 0.5f;
        sh.f.det[q][0] = d0; sh.f.det[q][1] = d1;
        sh.f.det[q][2] = d2; sh.f.det[q][3] = d3;
        sh.f.det[q][16] = s;
        sh.f.sbox[q] = make_float4(d0, d1, d2, d3);
        float kp[12] = {r1.x, r1.y, r1.z, r1.w,
                        r2.x, r2.y, r2.z, r2.w,
                        r3.x, r3.y, r3.z, r3.w};
        #pragma unroll
        for (int t = 0; t < 6; ++t) {
            sh.f.det[q][4 + 2 * t] = kp[2 * t]     / 128.0f * aw + ax;
            sh.f.det[q][5 + 2 * t] = kp[2 * t + 1] / 128.0f * ah + ay;
        }
    }
    __syncthreads();

    // ---- Phase 3: overlap bitmatrix, one u32 word (32 cols) per thread ----
    const int words = (C + 31) >> 5;
    for (int u = tid; u < C * words; u += 512) {
        int w = u / C;
        int row = u - w * C;
        int kbase = w << 5;
        int ke = C - kbase; if (ke > 32) ke = 32;
        float4 sb = sh.f.sbox[row];
        float ar = (sb.z - sb.x) * (sb.w - sb.y);
        u32 mm = 0, bit = 1u;
        #pragma unroll 4
        for (int k = 0; k < ke; ++k, bit <<= 1) {
            float4 bk = sh.f.sbox[kbase + k];
            float ak = (bk.z - bk.x) * (bk.w - bk.y);
            float i0 = fmaxf(sb.x, bk.x), i1 = fmaxf(sb.y, bk.y);
            float i2 = fminf(sb.z, bk.z), i3 = fminf(sb.w, bk.w);
            float inter = (i2 - i0) * (i3 - i1);
            float qq = inter / (ar + ak - inter);   // NaN -> no bit
            if (qq > 0.3f) mm |= bit;
        }
        sh.f.mat32[row][w] = mm;
    }
    __syncthreads();

    // ---- Phase 4: wave 0 pick-set scan; waves 1-7 zero out-tile + cl ----
    if (wv == 0) {
        const u32 (*M)[6] = sh.f.mat32;
        u64 m00 = (u64)M[lane][0]      | ((u64)M[lane][1] << 32);
        u64 m01 = (u64)M[lane][2]      | ((u64)M[lane][3] << 32);
        u64 m10 = (u64)M[lane + 64][0] | ((u64)M[lane + 64][1] << 32);
        u64 m11 = (u64)M[lane + 64][2] | ((u64)M[lane + 64][3] << 32);
        u64 rem0 = (C >= 64)  ? ~0ull : ((C > 0)   ? ((1ull << C) - 1)         : 0ull);
        u64 rem1 = (C >= 128) ? ~0ull : ((C > 64)  ? ((1ull << (C - 64)) - 1)  : 0ull);
        u64 rem2 = (C >= 192) ? ~0ull : ((C > 128) ? ((1ull << (C - 128)) - 1) : 0ull);
        u64 P0 = 0, P1 = 0, P2 = 0;
        int stk = CAP;

        if (C <= 128) {                      // common case: 2 rl64 per pick
            while (rem0) {
                int i = (int)__builtin_ctzll(rem0);
                u64 r0 = rl64(m00, i), r1 = rl64(m01, i);
                if (!((r0 >> i) & 1ull)) { stk = i; break; }
                P0 |= 1ull << i;
                rem0 &= ~r0; rem1 &= ~r1;
            }
            if (stk == CAP) while (rem1) {
                int i = (int)__builtin_ctzll(rem1);
                u64 r1 = rl64(m11, i);
                if (!((r1 >> i) & 1ull)) { stk = 64 + i; break; }
                P1 |= 1ull << i;
                rem1 &= ~r1;
            }
        } else {
            u64 m02 = (u64)M[lane][4]       | ((u64)M[lane][5] << 32);
            u64 m12 = (u64)M[lane + 64][4]  | ((u64)M[lane + 64][5] << 32);
            u64 m20 = (u64)M[lane + 128][0] | ((u64)M[lane + 128][1] << 32);
            u64 m21 = (u64)M[lane + 128][2] | ((u64)M[lane + 128][3] << 32);
            u64 m22 = (u64)M[lane + 128][4] | ((u64)M[lane + 128][5] << 32);
            while (rem0) {
                int i = (int)__builtin_ctzll(rem0);
                u64 r0 = rl64(m00, i), r1 = rl64(m01, i), r2 = rl64(m02, i);
                if (!((r0 >> i) & 1ull)) { stk = i; break; }
                P0 |= 1ull << i;
                rem0 &= ~r0; rem1 &= ~r1; rem2 &= ~r2;
            }
            if (stk == CAP) while (rem1) {
                int i = (int)__builtin_ctzll(rem1);
                u64 r1 = rl64(m11, i), r2 = rl64(m12, i);
                if (!((r1 >> i) & 1ull)) { stk = 64 + i; break; }
                P1 |= 1ull << i;
                rem1 &= ~r1; rem2 &= ~r2;
            }
            if (stk == CAP) while (rem2) {
                int i = (int)__builtin_ctzll(rem2);
                u64 r2 = rl64(m22, i);
                if (!((r2 >> i) & 1ull)) { stk = 128 + i; break; }
                P2 |= 1ull << i;
                rem2 &= ~r2;
            }
            (void)m20; (void)m21;   // loaded for symmetry; picks come via rem order
        }
        if (lane == 0) { Psh[0] = P0; Psh[1] = P1; Psh[2] = P2; stuck_sh = stk; }
    } else {
        for (int t = tid - 64; t < CAP * 6;     t += 448) ((u32*)sh.f.cl)[t] = 0u;
        for (int t = tid - 64; t < MAXDET * 17; t += 448) out_b[t] = 0.0f;
        for (int t = tid - 64; t < MAXDET;      t += 448) flg_b[t] = 0.0f;
    }
    __syncthreads();

    const u64 P0 = Psh[0], P1 = Psh[1], P2 = Psh[2];
    const int stuck_v = stuck_sh;

    // ---- Phase 5: parallel remover-scatter: cl[fc(k)] |= bit(k) ----
    if (tid < C) {
        u64 q0 = ((u64)sh.f.mat32[tid][0] | ((u64)sh.f.mat32[tid][1] << 32)) & P0;
        u64 q1 = ((u64)sh.f.mat32[tid][2] | ((u64)sh.f.mat32[tid][3] << 32)) & P1;
        u64 q2 = ((u64)sh.f.mat32[tid][4] | ((u64)sh.f.mat32[tid][5] << 32)) & P2;
        int fc = -1;
        if      (q0) fc = (int)__builtin_ctzll(q0);
        else if (q1) fc = 64  + (int)__builtin_ctzll(q1);
        else if (q2) fc = 128 + (int)__builtin_ctzll(q2);
        if (fc >= 0) atomicOr(&sh.f.cl[fc][tid >> 5], 1u << (tid & 31));
    }
    __syncthreads();

    // ---- Phase 6: parallel emission by pick rank ----
    const int Pn = (int)__popcll(P0) + (int)__popcll(P1) + (int)__popcll(P2);
    bool is_pick = false;
    if (tid < C) {
        is_pick = (tid < 64)  ? ((P0 >> tid) & 1ull)
                : (tid < 128) ? ((P1 >> (tid - 64)) & 1ull)
                              : ((P2 >> (tid - 128)) & 1ull);
    }
    if (is_pick) {
        int s;
        if (tid < 64)
            s = (int)__popcll(P0 & ((tid ? ((1ull << tid) - 1) : 0ull)));
        else if (tid < 128)
            s = (int)__popcll(P0)
              + (int)__popcll(P1 & (((tid - 64) ? ((1ull << (tid - 64)) - 1) : 0ull)));
        else
            s = (int)__popcll(P0) + (int)__popcll(P1)
              + (int)__popcll(P2 & (((tid - 128) ? ((1ull << (tid - 128)) - 1) : 0ull)));

        u64 c0 = (u64)sh.f.cl[tid][0] | ((u64)sh.f.cl[tid][1] << 32);
        u64 c1 = (u64)sh.f.cl[tid][2] | ((u64)sh.f.cl[tid][3] << 32);
        u64 c2 = (u64)sh.f.cl[tid][4] | ((u64)sh.f.cl[tid][5] << 32);
        int n = (int)__popcll(c0) + (int)__popcll(c1) + (int)__popcll(c2);
        float* orow = out_b + s * 17;
        if (n <= 1) {
            #pragma unroll
            for (int c = 0; c < 17; ++c) orow[c] = sh.f.det[tid][c];
        } else {
            float tot = 0.0f, wc[16];
            #pragma unroll
            for (int c = 0; c < 16; ++c) wc[c] = 0.0f;
            u64 m = c0;
            while (m) { int k = (int)__builtin_ctzll(m); m &= m - 1;
                float sc = sh.f.det[k][16]; tot += sc;
                #pragma unroll
                for (int c = 0; c < 16; ++c) wc[c] += sh.f.det[k][c] * sc; }
            m = c1;
            while (m) { int k = 64 + (int)__builtin_ctzll(m); m &= m - 1;
                float sc = sh.f.det[k][16]; tot += sc;
                #pragma unroll
                for (int c = 0; c < 16; ++c) wc[c] += sh.f.det[k][c] * sc; }
            m = c2;
            while (m) { int k = 128 + (int)__builtin_ctzll(m); m &= m - 1;
                float sc = sh.f.det[k][16]; tot += sc;
                #pragma unroll
                for (int c = 0; c < 16; ++c) wc[c] += sh.f.det[k][c] * sc; }
            float safe = (tot > 0.0f) ? tot : 1.0f;
            #pragma unroll
            for (int c = 0; c < 16; ++c) orow[c] = wc[c] / safe;
            orow[16] = tot / (float)n;
        }
        flg_b[s] = 1.0f;
    }
    // frozen-tail replication for the (unreachable) degenerate case
    if (stuck_v < CAP) {
        for (int s2 = Pn + tid; s2 < MAXDET; s2 += 512) {
            float* orow = out_b + s2 * 17;
            #pragma unroll
            for (int c = 0; c < 17; ++c) orow[c] = sh.f.det[stuck_v][c];
            flg_b[s2] = 1.0f;
        }
    }
}

extern "C" void kernel_launch(void* const* d_in, const int* in_sizes, int n_in,
                              void* d_out, int out_size, void* d_ws, size_t ws_size,
                              hipStream_t stream) {
    const float* raw_box   = (const float*)d_in[0];
    const float* raw_score = (const float*)d_in[1];
    const float* anchors   = (const float*)d_in[2];
    float* out   = (float*)d_out;
    float* flags = out + (size_t)NBATCH * MAXDET * 17;
    int has_ws = (ws_size >= (size_t)NBATCH * NA * 17 * sizeof(float)) ? 1 : 0;
    nms_kernel<<<NBATCH, 512, 0, stream>>>(raw_box, raw_score, anchors, out, flags,
                                           (float*)d_ws, has_ws);
}

// Round 10
// 25.921 us; speedup vs baseline: 2.6886x; 1.2366x over previous
//
#include <hip/hip_runtime.h>
#include <math.h>

#pragma clang fp contract(off)

#define NA      896
#define MAXDET  256
#define NBATCH  512
#define CAP     192
#define NCHUNK  14

typedef unsigned long long u64;
typedef unsigned int u32;

__device__ __forceinline__ u64 rl64(u64 v, int l) {
    u32 lo = __builtin_amdgcn_readlane((u32)v, l);
    u32 hi = __builtin_amdgcn_readlane((u32)(v >> 32), l);
    return ((u64)hi << 32) | (u64)lo;
}

struct FastSh {                 // ~30 KB
    float  det[CAP][17];
    float4 sbox[CAP];
    u64    keys[CAP];
    int    slot_a[CAP];
    float  slot_s[CAP];
    int    rankv[CAP];
    u32    mat32[CAP][6];
    u32    cl[CAP][6];
};
struct SlowSh {                 // ~18 KB (correctness-only path, C > CAP)
    float  score[NA];
    float4 box[NA];
    u64    remw[NCHUNK];
};
union ShU { FastSh f; SlowSh s; };

// One batch per 8-wave block. Pick set = lexicographically-first MIS of the
// symmetric overlap graph, computed by parallel fixpoint iteration of
// F(P) = {i : no smaller overlapping j in P}; converged fixpoint == greedy
// set (unique fixpoint, induction on index) -> bit-exact. Serial-scan
// fallback covers non-convergence and degenerate self-bit cases.
__global__ __launch_bounds__(512, 4) void nms_kernel(
    const float* __restrict__ raw_box,
    const float* __restrict__ raw_score,
    const float* __restrict__ anchors,
    float* __restrict__ out,
    float* __restrict__ flags,
    float* __restrict__ gws, int has_ws)
{
    __shared__ ShU sh;
    __shared__ u64 Psh[3];
    __shared__ int stuck_sh;
    __shared__ int cnt[NCHUNK];

    const int b    = blockIdx.x;
    const int tid  = threadIdx.x;
    const int lane = tid & 63;
    const int wv   = tid >> 6;

    const float* sc_base = raw_score + (size_t)b * NA;
    float* out_b = out   + (size_t)b * MAXDET * 17;
    float* flg_b = flags + (size_t)b * MAXDET;

    // ---- Phase 1a: scores + per-chunk ballots ----
    float s_r[2]; u64 bal_r[2]; bool v_r[2];
    #pragma unroll
    for (int r = 0; r < 2; ++r) {
        int c = wv + r * 8;
        s_r[r] = 0.0f; bal_r[r] = 0ull; v_r[r] = false;
        if (c < NCHUNK) {
            int a = c * 64 + lane;
            float x = sc_base[a];
            x = fminf(fmaxf(x, -100.0f), 100.0f);
            float s = 1.0f / (1.0f + expf(-x));
            bool v = (s >= 0.75f);
            u64 bal = __ballot(v);
            s_r[r] = s; bal_r[r] = bal; v_r[r] = v;
            if (lane == 0) cnt[c] = (int)__popcll(bal);
        }
    }
    __syncthreads();

    // ---- Phase 1b: prefix + scatter (keys carry anchor tiebreak) ----
    int cn[NCHUNK];
    #pragma unroll
    for (int j = 0; j < NCHUNK; ++j) cn[j] = cnt[j];
    int C = 0;
    #pragma unroll
    for (int j = 0; j < NCHUNK; ++j) C += cn[j];

    if (C > CAP) {
        // ================= slow path: correctness-only =================
        if (!has_ws) {
            for (int t = tid; t < MAXDET * 17; t += 512) out_b[t] = 0.0f;
            for (int t = tid; t < MAXDET;      t += 512) flg_b[t] = 0.0f;
            return;
        }
        float* gdet = gws + (size_t)b * NA * 17;
        for (int a0 = tid; a0 < NA; a0 += 512) {
            float x = sc_base[a0];
            x = fminf(fmaxf(x, -100.0f), 100.0f);
            float s = 1.0f / (1.0f + expf(-x));
            const float4 an = ((const float4*)anchors)[a0];
            const float4* rb = (const float4*)(raw_box + ((size_t)b * NA + a0) * 16);
            float4 r0 = rb[0], r1 = rb[1], r2 = rb[2], r3 = rb[3];
            float ax = an.x, ay = an.y, aw = an.z, ah = an.w;
            float xc = r0.x / 128.0f * aw + ax;
            float yc = r0.y / 128.0f * ah + ay;
            float w  = r0.z / 128.0f * aw;
            float h  = r0.w / 128.0f * ah;
            float d0 = yc - h * 0.5f, d1 = xc - w * 0.5f;
            float d2 = yc + h * 0.5f, d3 = xc + w * 0.5f;
            sh.s.score[a0] = s;
            sh.s.box[a0]   = make_float4(d0, d1, d2, d3);
            float* gr = gdet + (size_t)a0 * 17;
            gr[0] = d0; gr[1] = d1; gr[2] = d2; gr[3] = d3;
            float kp[12] = {r1.x, r1.y, r1.z, r1.w,
                            r2.x, r2.y, r2.z, r2.w,
                            r3.x, r3.y, r3.z, r3.w};
            #pragma unroll
            for (int t = 0; t < 6; ++t) {
                gr[4 + 2 * t] = kp[2 * t]     / 128.0f * aw + ax;
                gr[5 + 2 * t] = kp[2 * t + 1] / 128.0f * ah + ay;
            }
            gr[16] = s;
            u64 bal = __ballot(s >= 0.75f);
            if (lane == 0) sh.s.remw[a0 >> 6] = bal;
        }
        __syncthreads();
        if (wv == 0) {
            int step = 0;
            for (; step < MAXDET; ++step) {
                u64 best = 0;
                for (int c = 0; c < NCHUNK; ++c) {
                    if ((sh.s.remw[c] >> lane) & 1ull) {
                        int a = c * 64 + lane;
                        u64 key = ((u64)__float_as_uint(sh.s.score[a]) << 10)
                                | (u64)(1023 - a);
                        if (key > best) best = key;
                    }
                }
                #pragma unroll
                for (int off = 32; off; off >>= 1) {
                    u64 o = __shfl_xor(best, off);
                    if (o > best) best = o;
                }
                if (best == 0) break;
                int idx = 1023 - (int)(best & 1023ull);
                float4 bb = sh.s.box[idx];
                float areaA = (bb.z - bb.x) * (bb.w - bb.y);
                u32 ov = 0; int n = 0;
                for (int c = 0; c < NCHUNK; ++c) {
                    bool o = false;
                    if ((sh.s.remw[c] >> lane) & 1ull) {
                        int a = c * 64 + lane;
                        float4 cb = sh.s.box[a];
                        float i0 = fmaxf(bb.x, cb.x), i1 = fmaxf(bb.y, cb.y);
                        float i2 = fminf(bb.z, cb.z), i3 = fminf(bb.w, cb.w);
                        float inter = (i2 - i0) * (i3 - i1);
                        float areaB = (cb.z - cb.x) * (cb.w - cb.y);
                        float q = inter / (areaA + areaB - inter);
                        o = (q > 0.3f);
                    }
                    u64 balc = __ballot(o);
                    if (o) ov |= 1u << c;
                    n += (int)__popcll(balc);
                    if (lane == 0) sh.s.remw[c] &= ~balc;
                }
                if (n <= 1) {
                    if (lane < 17) out_b[step * 17 + lane] = gdet[(size_t)idx * 17 + lane];
                    if (lane == 17) flg_b[step] = 1.0f;
                } else {
                    float tot = 0.0f, wcv[16];
                    #pragma unroll
                    for (int j = 0; j < 16; ++j) wcv[j] = 0.0f;
                    for (int c = 0; c < NCHUNK; ++c) {
                        if ((ov >> c) & 1u) {
                            int a = c * 64 + lane;
                            float s2 = sh.s.score[a]; tot += s2;
                            #pragma unroll
                            for (int j = 0; j < 16; ++j)
                                wcv[j] += gdet[(size_t)a * 17 + j] * s2;
                        }
                    }
                    #pragma unroll
                    for (int off = 32; off; off >>= 1) {
                        tot += __shfl_xor(tot, off);
                        #pragma unroll
                        for (int j = 0; j < 16; ++j) wcv[j] += __shfl_xor(wcv[j], off);
                    }
                    if (lane == 0) {
                        float safe = (tot > 0.0f) ? tot : 1.0f;
                        #pragma unroll
                        for (int j = 0; j < 16; ++j) out_b[step * 17 + j] = wcv[j] / safe;
                        out_b[step * 17 + 16] = tot / (float)n;
                        flg_b[step] = 1.0f;
                    }
                }
            }
            for (int t = step * 17 + lane; t < MAXDET * 17; t += 64) out_b[t] = 0.0f;
            for (int t = step + lane;      t < MAXDET;      t += 64) flg_b[t] = 0.0f;
        }
        return;
        // ===============================================================
    }

    #pragma unroll
    for (int r = 0; r < 2; ++r) {
        int c = wv + r * 8;
        if (c < NCHUNK && v_r[r]) {
            int base = 0;
            #pragma unroll
            for (int j = 0; j < NCHUNK; ++j) base += (j < c) ? cn[j] : 0;
            int slot = base + (int)__popcll(bal_r[r] & ((1ull << lane) - 1ull));
            int a = c * 64 + lane;
            sh.f.keys[slot]   = ((u64)__float_as_uint(s_r[r]) << 10) | (u64)(1023 - a);
            sh.f.slot_a[slot] = a;
            sh.f.slot_s[slot] = s_r[r];
        }
    }
    __syncthreads();

    // ---- Phase 2a: issue gather loads + ballot-rank all keys ----
    float4 an, g0, g1, g2, g3; float s_my = 0.0f;
    if (tid < C) {
        int a_my = sh.f.slot_a[tid];
        s_my = sh.f.slot_s[tid];
        an = ((const float4*)anchors)[a_my];
        const float4* rb = (const float4*)(raw_box + ((size_t)b * NA + a_my) * 16);
        g0 = rb[0]; g1 = rb[1]; g2 = rb[2]; g3 = rb[3];
    }
    {
        u64 k0 = (lane < C)       ? sh.f.keys[lane]       : 0ull;
        u64 k1 = (lane + 64 < C)  ? sh.f.keys[lane + 64]  : 0ull;
        u64 k2 = (lane + 128 < C) ? sh.f.keys[lane + 128] : 0ull;
        for (int r = 0; ; ++r) {
            int i = wv + r * 8;
            if (i >= C) break;
            u64 ki = sh.f.keys[i];
            int q = (int)__popcll(__ballot(k0 > ki))
                  + (int)__popcll(__ballot(k1 > ki))
                  + (int)__popcll(__ballot(k2 > ki));
            if (lane == 0) sh.f.rankv[i] = q;
        }
    }
    __syncthreads();

    // ---- Phase 2b: decode into sorted position det[q] ----
    if (tid < C) {
        int q = sh.f.rankv[tid];
        float ax = an.x, ay = an.y, aw = an.z, ah = an.w;
        float xc = g0.x / 128.0f * aw + ax;
        float yc = g0.y / 128.0f * ah + ay;
        float w  = g0.z / 128.0f * aw;
        float h  = g0.w / 128.0f * ah;
        float d0 = yc - h * 0.5f, d1 = xc - w * 0.5f;
        float d2 = yc + h * 0.5f, d3 = xc + w * 0.5f;
        sh.f.det[q][0] = d0; sh.f.det[q][1] = d1;
        sh.f.det[q][2] = d2; sh.f.det[q][3] = d3;
        sh.f.det[q][16] = s_my;
        sh.f.sbox[q] = make_float4(d0, d1, d2, d3);
        float kp[12] = {g1.x, g1.y, g1.z, g1.w,
                        g2.x, g2.y, g2.z, g2.w,
                        g3.x, g3.y, g3.z, g3.w};
        #pragma unroll
        for (int t = 0; t < 6; ++t) {
            sh.f.det[q][4 + 2 * t] = kp[2 * t]     / 128.0f * aw + ax;
            sh.f.det[q][5 + 2 * t] = kp[2 * t + 1] / 128.0f * ah + ay;
        }
    }
    __syncthreads();

    // ---- Phase 3: overlap bitmatrix, one u32 word (32 cols) per thread ----
    const int words = (C + 31) >> 5;
    for (int u = tid; u < C * words; u += 512) {
        int w = u / C;
        int row = u - w * C;
        int kbase = w << 5;
        int ke = C - kbase; if (ke > 32) ke = 32;
        float4 sb = sh.f.sbox[row];
        float ar = (sb.z - sb.x) * (sb.w - sb.y);
        u32 mm = 0, bit = 1u;
        #pragma unroll 4
        for (int k = 0; k < ke; ++k, bit <<= 1) {
            float4 bk = sh.f.sbox[kbase + k];
            float ak = (bk.z - bk.x) * (bk.w - bk.y);
            float i0 = fmaxf(sb.x, bk.x), i1 = fmaxf(sb.y, bk.y);
            float i2 = fminf(sb.z, bk.z), i3 = fminf(sb.w, bk.w);
            float inter = (i2 - i0) * (i3 - i1);
            float qq = inter / (ar + ak - inter);   // NaN -> no bit
            if (qq > 0.3f) mm |= bit;
        }
        sh.f.mat32[row][w] = mm;
    }
    __syncthreads();

    // ---- Phase 4: wave 0 pick set (fixpoint MIS); waves 1-7 zero-fill ----
    if (wv == 0) {
        const u32 (*M)[6] = sh.f.mat32;
        const bool vA = (lane < C), vB = (lane + 64 < C), vC = (lane + 128 < C);
        u64 A0 = vA ? ((u64)M[lane][0]       | ((u64)M[lane][1] << 32))       : 0ull;
        u64 B0 = vB ? ((u64)M[lane + 64][0]  | ((u64)M[lane + 64][1] << 32))  : 0ull;
        u64 B1 = vB ? ((u64)M[lane + 64][2]  | ((u64)M[lane + 64][3] << 32))  : 0ull;
        u64 C0 = vC ? ((u64)M[lane + 128][0] | ((u64)M[lane + 128][1] << 32)) : 0ull;
        u64 C1 = vC ? ((u64)M[lane + 128][2] | ((u64)M[lane + 128][3] << 32)) : 0ull;
        u64 C2 = vC ? ((u64)M[lane + 128][4] | ((u64)M[lane + 128][5] << 32)) : 0ull;

        const u64 bel = lane ? ((1ull << lane) - 1ull) : 0ull;
        const u64 F0 = (C >= 64)  ? ~0ull : ((C > 0)   ? ((1ull << C) - 1)         : 0ull);
        const u64 F1 = (C >= 128) ? ~0ull : ((C > 64)  ? ((1ull << (C - 64)) - 1)  : 0ull);
        const u64 F2 = (C >= 192) ? ~0ull : ((C > 128) ? ((1ull << (C - 128)) - 1) : 0ull);

        bool degen = (__ballot((vA && !((A0 >> lane) & 1ull)) ||
                               (vB && !((B1 >> lane) & 1ull)) ||
                               (vC && !((C2 >> lane) & 1ull))) != 0ull);
        u64 P0 = F0, P1 = F1, P2 = F2;
        bool ok = false;
        if (!degen) {
            for (int round = 0; round < 32; ++round) {
                bool a0 = vA && !(A0 & P0 & bel);
                bool a1 = vB && !((B0 & P0) | (B1 & P1 & bel));
                bool a2 = vC && !((C0 & P0) | (C1 & P1) | (C2 & P2 & bel));
                u64 n0 = __ballot(a0), n1 = __ballot(a1), n2 = __ballot(a2);
                if (n0 == P0 && n1 == P1 && n2 == P2) { ok = true; break; }
                P0 = n0; P1 = n1; P2 = n2;
            }
        }
        int stk = CAP;
        if (!ok) {
            // serial fallback (bit-exact incl. degenerate freeze semantics)
            u64 r00 = vA ? ((u64)M[lane][0]       | ((u64)M[lane][1] << 32))       : 0ull;
            u64 r01 = vA ? ((u64)M[lane][2]       | ((u64)M[lane][3] << 32))       : 0ull;
            u64 r02 = vA ? ((u64)M[lane][4]       | ((u64)M[lane][5] << 32))       : 0ull;
            u64 r11 = B1;
            u64 r12 = vB ? ((u64)M[lane + 64][4]  | ((u64)M[lane + 64][5] << 32))  : 0ull;
            u64 r22 = C2;
            u64 rem0 = F0, rem1 = F1, rem2 = F2;
            P0 = 0; P1 = 0; P2 = 0;
            while (rem0) {
                int i = (int)__builtin_ctzll(rem0);
                u64 w0 = rl64(r00, i), w1 = rl64(r01, i), w2 = rl64(r02, i);
                if (!((w0 >> i) & 1ull)) { stk = i; break; }
                P0 |= 1ull << i;
                rem0 &= ~w0; rem1 &= ~w1; rem2 &= ~w2;
            }
            if (stk == CAP) while (rem1) {
                int i = (int)__builtin_ctzll(rem1);
                u64 w1 = rl64(r11, i), w2 = rl64(r12, i);
                if (!((w1 >> i) & 1ull)) { stk = 64 + i; break; }
                P1 |= 1ull << i;
                rem1 &= ~w1; rem2 &= ~w2;
            }
            if (stk == CAP) while (rem2) {
                int i = (int)__builtin_ctzll(rem2);
                u64 w2 = rl64(r22, i);
                if (!((w2 >> i) & 1ull)) { stk = 128 + i; break; }
                P2 |= 1ull << i;
                rem2 &= ~w2;
            }
        }
        if (lane == 0) { Psh[0] = P0; Psh[1] = P1; Psh[2] = P2; stuck_sh = stk; }
    } else {
        for (int t = tid - 64; t < CAP * 6;     t += 448) ((u32*)sh.f.cl)[t] = 0u;
        for (int t = tid - 64; t < MAXDET * 17; t += 448) out_b[t] = 0.0f;
        for (int t = tid - 64; t < MAXDET;      t += 448) flg_b[t] = 0.0f;
    }
    __syncthreads();

    const u64 P0 = Psh[0], P1 = Psh[1], P2 = Psh[2];
    const int stuck_v = stuck_sh;

    // ---- Phase 5: parallel remover-scatter: cl[fc(k)] |= bit(k) ----
    if (tid < C) {
        u64 q0 = ((u64)sh.f.mat32[tid][0] | ((u64)sh.f.mat32[tid][1] << 32)) & P0;
        u64 q1 = ((u64)sh.f.mat32[tid][2] | ((u64)sh.f.mat32[tid][3] << 32)) & P1;
        u64 q2 = ((u64)sh.f.mat32[tid][4] | ((u64)sh.f.mat32[tid][5] << 32)) & P2;
        int fc = -1;
        if      (q0) fc = (int)__builtin_ctzll(q0);
        else if (q1) fc = 64  + (int)__builtin_ctzll(q1);
        else if (q2) fc = 128 + (int)__builtin_ctzll(q2);
        if (fc >= 0) atomicOr(&sh.f.cl[fc][tid >> 5], 1u << (tid & 31));
    }
    __syncthreads();

    // ---- Phase 6: parallel emission by pick rank ----
    bool is_pick = false;
    if (tid < C) {
        is_pick = (tid < 64)  ? ((P0 >> tid) & 1ull)
                : (tid < 128) ? ((P1 >> (tid - 64)) & 1ull)
                              : ((P2 >> (tid - 128)) & 1ull);
    }
    if (is_pick && tid < ((stuck_v < CAP) ? stuck_v : CAP)) {
        int s;
        if (tid < 64)
            s = (int)__popcll(P0 & ((tid ? ((1ull << tid) - 1) : 0ull)));
        else if (tid < 128)
            s = (int)__popcll(P0)
              + (int)__popcll(P1 & (((tid - 64) ? ((1ull << (tid - 64)) - 1) : 0ull)));
        else
            s = (int)__popcll(P0) + (int)__popcll(P1)
              + (int)__popcll(P2 & (((tid - 128) ? ((1ull << (tid - 128)) - 1) : 0ull)));

        u64 c0 = (u64)sh.f.cl[tid][0] | ((u64)sh.f.cl[tid][1] << 32);
        u64 c1 = (u64)sh.f.cl[tid][2] | ((u64)sh.f.cl[tid][3] << 32);
        u64 c2 = (u64)sh.f.cl[tid][4] | ((u64)sh.f.cl[tid][5] << 32);
        int n = (int)__popcll(c0) + (int)__popcll(c1) + (int)__popcll(c2);
        float* orow = out_b + s * 17;
        if (n <= 1) {
            #pragma unroll
            for (int c = 0; c < 17; ++c) orow[c] = sh.f.det[tid][c];
        } else {
            float tot = 0.0f, wc[16];
            #pragma unroll
            for (int c = 0; c < 16; ++c) wc[c] = 0.0f;
            u64 m = c0;
            while (m) { int k = (int)__builtin_ctzll(m); m &= m - 1;
                float sc = sh.f.det[k][16]; tot += sc;
                #pragma unroll
                for (int c = 0; c < 16; ++c) wc[c] += sh.f.det[k][c] * sc; }
            m = c1;
            while (m) { int k = 64 + (int)__builtin_ctzll(m); m &= m - 1;
                float sc = sh.f.det[k][16]; tot += sc;
                #pragma unroll
                for (int c = 0; c < 16; ++c) wc[c] += sh.f.det[k][c] * sc; }
            m = c2;
            while (m) { int k = 128 + (int)__builtin_ctzll(m); m &= m - 1;
                float sc = sh.f.det[k][16]; tot += sc;
                #pragma unroll
                for (int c = 0; c < 16; ++c) wc[c] += sh.f.det[k][c] * sc; }
            float safe = (tot > 0.0f) ? tot : 1.0f;
            #pragma unroll
            for (int c = 0; c < 16; ++c) orow[c] = wc[c] / safe;
            orow[16] = tot / (float)n;
        }
        flg_b[s] = 1.0f;
    }
    // frozen-tail replication for the (unreachable) degenerate case
    if (stuck_v < CAP) {
        int Pb = 0;   // picks before the stuck index
        {
            u64 t0 = P0, t1 = P1, t2 = P2;
            if (stuck_v < 64)       { t0 &= (stuck_v ? ((1ull << stuck_v) - 1) : 0ull); t1 = 0; t2 = 0; }
            else if (stuck_v < 128) { t1 &= (((stuck_v - 64) ? ((1ull << (stuck_v - 64)) - 1) : 0ull)); t2 = 0; }
            else                    { t2 &= (((stuck_v - 128) ? ((1ull << (stuck_v - 128)) - 1) : 0ull)); }
            Pb = (int)__popcll(t0) + (int)__popcll(t1) + (int)__popcll(t2);
        }
        for (int s2 = Pb + tid; s2 < MAXDET; s2 += 512) {
            float* orow = out_b + s2 * 17;
            #pragma unroll
            for (int c = 0; c < 17; ++c) orow[c] = sh.f.det[stuck_v][c];
            flg_b[s2] = 1.0f;
        }
    }
}

extern "C" void kernel_launch(void* const* d_in, const int* in_sizes, int n_in,
                              void* d_out, int out_size, void* d_ws, size_t ws_size,
                              hipStream_t stream) {
    const float* raw_box   = (const float*)d_in[0];
    const float* raw_score = (const float*)d_in[1];
    const float* anchors   = (const float*)d_in[2];
    float* out   = (float*)d_out;
    float* flags = out + (size_t)NBATCH * MAXDET * 17;
    int has_ws = (ws_size >= (size_t)NBATCH * NA * 17 * sizeof(float)) ? 1 : 0;
    nms_kernel<<<NBATCH, 512, 0, stream>>>(raw_box, raw_score, anchors, out, flags,
                                           (float*)d_ws, has_ws);
}